// Round 1
// baseline (1844.094 us; speedup 1.0000x reference)
//
#include <hip/hip_runtime.h>
#include <math.h>

#define T_DIM 2048
#define D_DIM 2048
#define NHEAD 16
#define DHEAD 128

// ---------------------------------------------------------------------------
// GEMM: C[M,N] = A[M,K] @ W[N,K]^T + bias[N]    (M=N=K=2048, all row-major)
// Tiles: BM=BN=64, BK=32. 256 threads, 4x4 micro-tile per thread.
// LDS staged transposed (As[k][m]) with +4 pad so compute reads ds_read_b128.
// ---------------------------------------------------------------------------
constexpr int BM = 64, BN = 64, BK = 32;

__global__ __launch_bounds__(256) void gemm_bias_bt(
    const float* __restrict__ A, const float* __restrict__ W,
    const float* __restrict__ bias, float* __restrict__ C)
{
    __shared__ float As[BK][BM + 4];
    __shared__ float Ws[BK][BN + 4];
    const int tid = threadIdx.x;
    const int n0 = blockIdx.x * BN;
    const int m0 = blockIdx.y * BM;
    const int tx = tid & 15;   // n sub-tile
    const int ty = tid >> 4;   // m sub-tile

    float acc[4][4] = {};

    for (int k0 = 0; k0 < D_DIM; k0 += BK) {
        __syncthreads();
#pragma unroll
        for (int i = 0; i < 2; ++i) {
            const int f = tid + i * 256;      // 0..511 float4 slots
            const int row = f >> 3;           // 0..63
            const int k4 = (f & 7) << 2;      // 0,4,...,28
            const float4 av = *reinterpret_cast<const float4*>(
                &A[(size_t)(m0 + row) * D_DIM + k0 + k4]);
            As[k4 + 0][row] = av.x; As[k4 + 1][row] = av.y;
            As[k4 + 2][row] = av.z; As[k4 + 3][row] = av.w;
            const float4 wv = *reinterpret_cast<const float4*>(
                &W[(size_t)(n0 + row) * D_DIM + k0 + k4]);
            Ws[k4 + 0][row] = wv.x; Ws[k4 + 1][row] = wv.y;
            Ws[k4 + 2][row] = wv.z; Ws[k4 + 3][row] = wv.w;
        }
        __syncthreads();
#pragma unroll
        for (int kk = 0; kk < BK; ++kk) {
            const float4 a = *reinterpret_cast<const float4*>(&As[kk][ty << 2]);
            const float4 w = *reinterpret_cast<const float4*>(&Ws[kk][tx << 2]);
            const float av[4] = {a.x, a.y, a.z, a.w};
            const float wv[4] = {w.x, w.y, w.z, w.w};
#pragma unroll
            for (int i = 0; i < 4; ++i)
#pragma unroll
                for (int j = 0; j < 4; ++j)
                    acc[i][j] = fmaf(av[i], wv[j], acc[i][j]);
        }
    }

    const float4 bv = *reinterpret_cast<const float4*>(&bias[n0 + (tx << 2)]);
#pragma unroll
    for (int i = 0; i < 4; ++i) {
        const int row = m0 + (ty << 2) + i;
        float4 o;
        o.x = acc[i][0] + bv.x; o.y = acc[i][1] + bv.y;
        o.z = acc[i][2] + bv.z; o.w = acc[i][3] + bv.w;
        *reinterpret_cast<float4*>(&C[(size_t)row * D_DIM + n0 + (tx << 2)]) = o;
    }
}

// ---------------------------------------------------------------------------
// Causal flash attention, fp32. One block = one (head, 32-row Q tile).
// 256 threads as (tx=0..31, ty=0..7); each thread owns rows {ty+8*rr} and,
// in the PV phase, dims {4*tx..4*tx+3}. Online softmax state in registers.
// ---------------------------------------------------------------------------
constexpr int BR = 32, BC = 32;
constexpr int KST = DHEAD + 4;  // 132 floats: keeps 16B alignment, breaks
                                // the stride-128 all-lanes-one-bank case.

__global__ __launch_bounds__(256) void attn_causal(
    const float* __restrict__ Q, const float* __restrict__ K,
    const float* __restrict__ V, float* __restrict__ Y)
{
    __shared__ float Qs[BR][KST];
    __shared__ float Ks[BC][KST];
    __shared__ float Vs[BC][KST];
    __shared__ float Ps[BR][BC + 1];

    const int h  = blockIdx.y;
    const int qt = blockIdx.x;
    const int q0 = qt * BR;
    const int tid = threadIdx.x;
    const int tx = tid & 31;
    const int ty = tid >> 5;
    const size_t hoff = (size_t)h * DHEAD;

    // stage Q tile (32 x 128) as float4, coalesced
#pragma unroll
    for (int i = 0; i < 4; ++i) {
        const int f = tid + i * 256;
        const int row = f >> 5;
        const int d4 = (f & 31) << 2;
        *reinterpret_cast<float4*>(&Qs[row][d4]) =
            *reinterpret_cast<const float4*>(
                &Q[(size_t)(q0 + row) * D_DIM + hoff + d4]);
    }

    float mrow[4], lrow[4], acc[4][4];
#pragma unroll
    for (int rr = 0; rr < 4; ++rr) {
        mrow[rr] = -INFINITY; lrow[rr] = 0.f;
        acc[rr][0] = acc[rr][1] = acc[rr][2] = acc[rr][3] = 0.f;
    }

    for (int j = 0; j <= qt; ++j) {
        __syncthreads();   // previous iter's readers of Ks/Vs/Ps are done
#pragma unroll
        for (int i = 0; i < 4; ++i) {
            const int f = tid + i * 256;
            const int row = f >> 5;
            const int d4 = (f & 31) << 2;
            *reinterpret_cast<float4*>(&Ks[row][d4]) =
                *reinterpret_cast<const float4*>(
                    &K[(size_t)(j * BC + row) * D_DIM + hoff + d4]);
            *reinterpret_cast<float4*>(&Vs[row][d4]) =
                *reinterpret_cast<const float4*>(
                    &V[(size_t)(j * BC + row) * D_DIM + hoff + d4]);
        }
        __syncthreads();

        // scores: this thread computes S[lr][tx] for lr = ty + 8*rr
        float s[4] = {0.f, 0.f, 0.f, 0.f};
#pragma unroll 8
        for (int d4 = 0; d4 < DHEAD; d4 += 4) {
            const float4 kv = *reinterpret_cast<const float4*>(&Ks[tx][d4]);
#pragma unroll
            for (int rr = 0; rr < 4; ++rr) {
                const float4 qv =
                    *reinterpret_cast<const float4*>(&Qs[ty + (rr << 3)][d4]);
                s[rr] = fmaf(qv.x, kv.x, s[rr]);
                s[rr] = fmaf(qv.y, kv.y, s[rr]);
                s[rr] = fmaf(qv.z, kv.z, s[rr]);
                s[rr] = fmaf(qv.w, kv.w, s[rr]);
            }
        }

        const bool diag = (j == qt);
#pragma unroll
        for (int rr = 0; rr < 4; ++rr) {
            const int lr = ty + (rr << 3);
            float sv = s[rr] * 0.08838834764831845f;  // 1/sqrt(128)
            if (diag && tx > lr) sv = -INFINITY;       // causal mask
            // row max over the 32 columns (lanes 0..31 / 32..63 separately)
            float mx = sv;
#pragma unroll
            for (int off = 16; off > 0; off >>= 1)
                mx = fmaxf(mx, __shfl_xor(mx, off));
            const float mnew = fmaxf(mrow[rr], mx);
            const float p = __expf(sv - mnew);         // -inf -> 0
            float rs = p;
#pragma unroll
            for (int off = 16; off > 0; off >>= 1)
                rs += __shfl_xor(rs, off);
            const float corr = __expf(mrow[rr] - mnew);
            lrow[rr] = lrow[rr] * corr + rs;
            mrow[rr] = mnew;
            Ps[lr][tx] = p;
            acc[rr][0] *= corr; acc[rr][1] *= corr;
            acc[rr][2] *= corr; acc[rr][3] *= corr;
        }
        __syncthreads();   // Ps visible to all

        // PV: acc[rr][0..3] covers dims 4*tx..4*tx+3 of rows ty+8*rr
#pragma unroll 8
        for (int c = 0; c < BC; ++c) {
            const float4 vv =
                *reinterpret_cast<const float4*>(&Vs[c][tx << 2]);
#pragma unroll
            for (int rr = 0; rr < 4; ++rr) {
                const float p = Ps[ty + (rr << 3)][c];
                acc[rr][0] = fmaf(p, vv.x, acc[rr][0]);
                acc[rr][1] = fmaf(p, vv.y, acc[rr][1]);
                acc[rr][2] = fmaf(p, vv.z, acc[rr][2]);
                acc[rr][3] = fmaf(p, vv.w, acc[rr][3]);
            }
        }
    }

#pragma unroll
    for (int rr = 0; rr < 4; ++rr) {
        const int lr = ty + (rr << 3);
        const float inv = 1.0f / lrow[rr];
        float4 o;
        o.x = acc[rr][0] * inv; o.y = acc[rr][1] * inv;
        o.z = acc[rr][2] * inv; o.w = acc[rr][3] * inv;
        *reinterpret_cast<float4*>(
            &Y[(size_t)(q0 + lr) * D_DIM + hoff + (tx << 2)]) = o;
    }
}

// ---------------------------------------------------------------------------
extern "C" void kernel_launch(void* const* d_in, const int* in_sizes, int n_in,
                              void* d_out, int out_size, void* d_ws, size_t ws_size,
                              hipStream_t stream)
{
    const float* x  = (const float*)d_in[0];
    const float* Wq = (const float*)d_in[1];
    const float* bq = (const float*)d_in[2];
    const float* Wk = (const float*)d_in[3];
    const float* bk = (const float*)d_in[4];
    const float* Wv = (const float*)d_in[5];
    const float* bv = (const float*)d_in[6];
    const float* Wo = (const float*)d_in[7];
    const float* bo = (const float*)d_in[8];
    float* out = (float*)d_out;

    const size_t mat = (size_t)T_DIM * D_DIM;
    float* Qb = (float*)d_ws;
    float* Kb = Qb + mat;
    float* Vb = Kb + mat;
    float* Yb = Vb + mat;

    const dim3 ggrid(D_DIM / BN, T_DIM / BM);
    gemm_bias_bt<<<ggrid, 256, 0, stream>>>(x, Wq, bq, Qb);
    gemm_bias_bt<<<ggrid, 256, 0, stream>>>(x, Wk, bk, Kb);
    gemm_bias_bt<<<ggrid, 256, 0, stream>>>(x, Wv, bv, Vb);
    attn_causal<<<dim3(T_DIM / BR, NHEAD), 256, 0, stream>>>(Qb, Kb, Vb, Yb);
    gemm_bias_bt<<<ggrid, 256, 0, stream>>>(Yb, Wo, bo, out);
}

// Round 2
// 636.527 us; speedup vs baseline: 2.8971x; 2.8971x over previous
//
#include <hip/hip_runtime.h>
#include <math.h>

#define T_DIM 2048
#define D_DIM 2048
#define NHEAD 16
#define DHEAD 128

typedef short v8s __attribute__((ext_vector_type(8)));   // 8 bf16 bit patterns
typedef float v4f __attribute__((ext_vector_type(4)));

#define MFMA16(a, b, c) __builtin_amdgcn_mfma_f32_16x16x32_bf16((a), (b), (c), 0, 0, 0)

__device__ __forceinline__ unsigned short f2bf(float f) {
    unsigned u = __float_as_uint(f);
    u += 0x7FFF + ((u >> 16) & 1);          // RNE
    return (unsigned short)(u >> 16);
}
__device__ __forceinline__ float bf2f(unsigned short h) {
    return __uint_as_float((unsigned)h << 16);
}
__device__ __forceinline__ unsigned pack2(unsigned short a, unsigned short b) {
    return (unsigned)a | ((unsigned)b << 16);
}

// ---------------------------------------------------------------------------
// split fp32 -> bf16 hi/lo (for x). 8 floats per thread.
// ---------------------------------------------------------------------------
__global__ __launch_bounds__(256) void split_x(
    const float* __restrict__ X, unsigned short* __restrict__ Xh,
    unsigned short* __restrict__ Xl)
{
    const int i = (blockIdx.x * 256 + threadIdx.x) * 8;
    const float4 a = *(const float4*)&X[i];
    const float4 b = *(const float4*)&X[i + 4];
    const float f[8] = {a.x, a.y, a.z, a.w, b.x, b.y, b.z, b.w};
    unsigned short h[8], l[8];
#pragma unroll
    for (int e = 0; e < 8; ++e) {
        h[e] = f2bf(f[e]);
        l[e] = f2bf(f[e] - bf2f(h[e]));
    }
    uint4 hv, lv;
    hv.x = pack2(h[0], h[1]); hv.y = pack2(h[2], h[3]);
    hv.z = pack2(h[4], h[5]); hv.w = pack2(h[6], h[7]);
    lv.x = pack2(l[0], l[1]); lv.y = pack2(l[2], l[3]);
    lv.z = pack2(l[4], l[5]); lv.w = pack2(l[6], l[7]);
    *(uint4*)&Xh[i] = hv;
    *(uint4*)&Xl[i] = lv;
}

// ---------------------------------------------------------------------------
// GEMM C = A @ W^T + bias, bf16x3 split precision.
//  A given as precomputed bf16 hi/lo arrays [2048][2048].
//  W fp32 [N][K], split hi/lo on the fly during LDS staging.
//  MODE 0: write bf16 ((acc+bias)*scale) row-major  (Q with scale, K)
//  MODE 1: write bf16 (acc+bias) TRANSPOSED [n][m]  (V -> Vt)
//  MODE 2: write fp32 (acc+bias) row-major           (final output)
// 512 threads = 8 waves (2x4), block tile 128x128, BK=64, wave tile 64x32.
// LDS rows padded to 72 bf16 (144 B): 4-way uniform = ds_read_b128 floor.
// ---------------------------------------------------------------------------
template <int MODE>
__global__ __launch_bounds__(512) void gemm_x3(
    const unsigned short* __restrict__ Ahg, const unsigned short* __restrict__ Alg,
    const float* __restrict__ W, const float* __restrict__ bias, float scale,
    unsigned short* __restrict__ Ob, float* __restrict__ Of)
{
    extern __shared__ char smem[];
    unsigned short* Ah = (unsigned short*)smem;         // [128][72]
    unsigned short* Al = Ah + 128 * 72;
    unsigned short* Bh = Al + 128 * 72;
    unsigned short* Bl = Bh + 128 * 72;

    const int tid = threadIdx.x;
    const int l   = tid & 63;
    const int wid = tid >> 6;
    const int wm  = wid >> 2;      // 0..1
    const int wn  = wid & 3;       // 0..3
    const int cl  = l & 15;
    const int rg  = l >> 4;
    const int m0  = blockIdx.y * 128;
    const int n0  = blockIdx.x * 128;

    // staging assignment
    const int arow = tid >> 3;     // 0..63 (and +64)
    const int akg  = tid & 7;
    const int brow = tid >> 2;     // 0..127
    const int bkq  = tid & 3;      // 0..3 (16 floats each)

    v4f acc[4][2];
#pragma unroll
    for (int i = 0; i < 4; ++i)
#pragma unroll
        for (int j = 0; j < 2; ++j) acc[i][j] = (v4f)0.f;

    uint4  ar[4];
    float4 br[4];

    auto load_tile = [&](int k0) {
        ar[0] = *(const uint4*)&Ahg[(size_t)(m0 + arow) * D_DIM + k0 + akg * 8];
        ar[1] = *(const uint4*)&Ahg[(size_t)(m0 + arow + 64) * D_DIM + k0 + akg * 8];
        ar[2] = *(const uint4*)&Alg[(size_t)(m0 + arow) * D_DIM + k0 + akg * 8];
        ar[3] = *(const uint4*)&Alg[(size_t)(m0 + arow + 64) * D_DIM + k0 + akg * 8];
        const size_t wb = (size_t)(n0 + brow) * D_DIM + k0 + bkq * 16;
        br[0] = *(const float4*)&W[wb];
        br[1] = *(const float4*)&W[wb + 4];
        br[2] = *(const float4*)&W[wb + 8];
        br[3] = *(const float4*)&W[wb + 12];
    };

    load_tile(0);

    for (int ks = 0; ks < D_DIM / 64; ++ks) {
        __syncthreads();
        // A: straight bf16 copy into padded LDS
        *(uint4*)&Ah[arow * 72 + akg * 8]        = ar[0];
        *(uint4*)&Ah[(arow + 64) * 72 + akg * 8] = ar[1];
        *(uint4*)&Al[arow * 72 + akg * 8]        = ar[2];
        *(uint4*)&Al[(arow + 64) * 72 + akg * 8] = ar[3];
        // B: split fp32 -> hi/lo, write 16+16 bf16
        {
            const float fv[16] = {br[0].x, br[0].y, br[0].z, br[0].w,
                                  br[1].x, br[1].y, br[1].z, br[1].w,
                                  br[2].x, br[2].y, br[2].z, br[2].w,
                                  br[3].x, br[3].y, br[3].z, br[3].w};
            unsigned short h[16], lo[16];
#pragma unroll
            for (int e = 0; e < 16; ++e) {
                h[e]  = f2bf(fv[e]);
                lo[e] = f2bf(fv[e] - bf2f(h[e]));
            }
            uint4 h0, h1, l0, l1;
            h0.x = pack2(h[0], h[1]);   h0.y = pack2(h[2], h[3]);
            h0.z = pack2(h[4], h[5]);   h0.w = pack2(h[6], h[7]);
            h1.x = pack2(h[8], h[9]);   h1.y = pack2(h[10], h[11]);
            h1.z = pack2(h[12], h[13]); h1.w = pack2(h[14], h[15]);
            l0.x = pack2(lo[0], lo[1]);   l0.y = pack2(lo[2], lo[3]);
            l0.z = pack2(lo[4], lo[5]);   l0.w = pack2(lo[6], lo[7]);
            l1.x = pack2(lo[8], lo[9]);   l1.y = pack2(lo[10], lo[11]);
            l1.z = pack2(lo[12], lo[13]); l1.w = pack2(lo[14], lo[15]);
            *(uint4*)&Bh[brow * 72 + bkq * 16]     = h0;
            *(uint4*)&Bh[brow * 72 + bkq * 16 + 8] = h1;
            *(uint4*)&Bl[brow * 72 + bkq * 16]     = l0;
            *(uint4*)&Bl[brow * 72 + bkq * 16 + 8] = l1;
        }
        if (ks + 1 < D_DIM / 64) load_tile((ks + 1) * 64);
        __syncthreads();

#pragma unroll
        for (int kf = 0; kf < 2; ++kf) {
            v8s a_h[4], a_l[4], b_h[2], b_l[2];
            const int kc = kf * 32 + rg * 8;
#pragma unroll
            for (int mf = 0; mf < 4; ++mf) {
                const int r = wm * 64 + mf * 16 + cl;
                a_h[mf] = *(const v8s*)&Ah[r * 72 + kc];
                a_l[mf] = *(const v8s*)&Al[r * 72 + kc];
            }
#pragma unroll
            for (int nf = 0; nf < 2; ++nf) {
                const int r = wn * 32 + nf * 16 + cl;
                b_h[nf] = *(const v8s*)&Bh[r * 72 + kc];
                b_l[nf] = *(const v8s*)&Bl[r * 72 + kc];
            }
#pragma unroll
            for (int mf = 0; mf < 4; ++mf)
#pragma unroll
                for (int nf = 0; nf < 2; ++nf) {
                    acc[mf][nf] = MFMA16(a_h[mf], b_h[nf], acc[mf][nf]);
                    acc[mf][nf] = MFMA16(a_h[mf], b_l[nf], acc[mf][nf]);
                    acc[mf][nf] = MFMA16(a_l[mf], b_h[nf], acc[mf][nf]);
                }
        }
    }

    // epilogue: C row = m0+wm*64+mf*16+rg*4+j, col = n0+wn*32+nf*16+cl
#pragma unroll
    for (int mf = 0; mf < 4; ++mf)
#pragma unroll
        for (int nf = 0; nf < 2; ++nf) {
            const int n = n0 + wn * 32 + nf * 16 + cl;
            const int mb = m0 + wm * 64 + mf * 16 + rg * 4;
            const float bv = bias[n];
            if (MODE == 0) {
#pragma unroll
                for (int j = 0; j < 4; ++j)
                    Ob[(size_t)(mb + j) * D_DIM + n] =
                        f2bf((acc[mf][nf][j] + bv) * scale);
            } else if (MODE == 1) {
                ushort4 pk;
                pk.x = f2bf(acc[mf][nf][0] + bv);
                pk.y = f2bf(acc[mf][nf][1] + bv);
                pk.z = f2bf(acc[mf][nf][2] + bv);
                pk.w = f2bf(acc[mf][nf][3] + bv);
                *(ushort4*)&Ob[(size_t)n * D_DIM + mb] = pk;   // Vt[n][m..m+3]
            } else {
#pragma unroll
                for (int j = 0; j < 4; ++j)
                    Of[(size_t)(mb + j) * D_DIM + n] = acc[mf][nf][j] + bv;
            }
        }
}

// ---------------------------------------------------------------------------
// Causal flash attention, bf16 MFMA.
// Block = 256 threads (4 waves), BR=64 Q rows (16/wave), BC=32 KV cols.
// Q frags in registers; K staged [32][136]; V staged transposed [128][40];
// P through LDS [64][40]. Online softmax in registers.
// Flat grid 512: blocks b and b+256 get qt and 31-qt (causal load balance).
// Writes Y as bf16 hi/lo (for the x3 O-projection).
// ---------------------------------------------------------------------------
__global__ __launch_bounds__(256) void attn_mfma(
    const unsigned short* __restrict__ Qg, const unsigned short* __restrict__ Kg,
    const unsigned short* __restrict__ Vtg,
    unsigned short* __restrict__ Yh, unsigned short* __restrict__ Yl)
{
    __shared__ unsigned short Ks[32 * 136];
    __shared__ unsigned short Vs[128 * 40];
    __shared__ unsigned short Ps[64 * 40];

    const int b   = blockIdx.x;
    const int h   = b & 15;
    const int idx = (b >> 4) & 15;
    const int qt  = (b >> 8) ? (31 - idx) : idx;
    const int q0  = qt * 64;
    const int tid = threadIdx.x;
    const int l   = tid & 63;
    const int w   = tid >> 6;
    const int cl  = l & 15;
    const int rg  = l >> 4;

    // Q fragments (scale already folded into Q by the Q-GEMM epilogue)
    v8s qf[4];
#pragma unroll
    for (int kf = 0; kf < 4; ++kf)
        qf[kf] = *(const v8s*)&Qg[(size_t)(q0 + w * 16 + cl) * D_DIM +
                                  h * DHEAD + kf * 32 + rg * 8];

    v4f acc[8];
#pragma unroll
    for (int nf = 0; nf < 8; ++nf) acc[nf] = (v4f)0.f;
    float mrow[4] = {-INFINITY, -INFINITY, -INFINITY, -INFINITY};
    float lsum[4] = {0.f, 0.f, 0.f, 0.f};

    const int krow = tid >> 4, kkg = tid & 15;   // K: rows 0..15 (+16)
    const int vrow = tid >> 2, vsg = tid & 3;    // Vt: rows 0..63 (+64)
    uint4 kr[2], vr[2];
    auto load_kv = [&](int j) {
        kr[0] = *(const uint4*)&Kg[(size_t)(j * 32 + krow) * D_DIM + h * DHEAD + kkg * 8];
        kr[1] = *(const uint4*)&Kg[(size_t)(j * 32 + krow + 16) * D_DIM + h * DHEAD + kkg * 8];
        vr[0] = *(const uint4*)&Vtg[(size_t)(h * DHEAD + vrow) * D_DIM + j * 32 + vsg * 8];
        vr[1] = *(const uint4*)&Vtg[(size_t)(h * DHEAD + vrow + 64) * D_DIM + j * 32 + vsg * 8];
    };

    load_kv(0);
    const int jmax = 2 * qt + 1;
    for (int j = 0; j <= jmax; ++j) {
        __syncthreads();                       // prev readers of Ks/Vs done
        *(uint4*)&Ks[krow * 136 + kkg * 8]        = kr[0];
        *(uint4*)&Ks[(krow + 16) * 136 + kkg * 8] = kr[1];
        *(uint4*)&Vs[vrow * 40 + vsg * 8]         = vr[0];
        *(uint4*)&Vs[(vrow + 64) * 40 + vsg * 8]  = vr[1];
        if (j < jmax) load_kv(j + 1);
        __syncthreads();

        // scores S[16 x 32] per wave
        v4f s[2];
        s[0] = (v4f)0.f; s[1] = (v4f)0.f;
#pragma unroll
        for (int kf = 0; kf < 4; ++kf) {
            const int kc = kf * 32 + rg * 8;
            s[0] = MFMA16(qf[kf], *(const v8s*)&Ks[cl * 136 + kc], s[0]);
            s[1] = MFMA16(qf[kf], *(const v8s*)&Ks[(16 + cl) * 136 + kc], s[1]);
        }

        // online softmax per owned row (rg*4 + j4)
#pragma unroll
        for (int j4 = 0; j4 < 4; ++j4) {
            const int row = q0 + w * 16 + rg * 4 + j4;
            float s0 = s[0][j4], s1 = s[1][j4];
            if (j * 32 + cl > row)      s0 = -INFINITY;
            if (j * 32 + 16 + cl > row) s1 = -INFINITY;
            float mx = fmaxf(s0, s1);
            mx = fmaxf(mx, __shfl_xor(mx, 1));
            mx = fmaxf(mx, __shfl_xor(mx, 2));
            mx = fmaxf(mx, __shfl_xor(mx, 4));
            mx = fmaxf(mx, __shfl_xor(mx, 8));
            const float mnew = fmaxf(mrow[j4], mx);
            const float p0 = __expf(s0 - mnew);
            const float p1 = __expf(s1 - mnew);
            float rs = p0 + p1;
            rs += __shfl_xor(rs, 1);
            rs += __shfl_xor(rs, 2);
            rs += __shfl_xor(rs, 4);
            rs += __shfl_xor(rs, 8);
            const float corr = __expf(mrow[j4] - mnew);
            lsum[j4] = lsum[j4] * corr + rs;
            mrow[j4] = mnew;
#pragma unroll
            for (int nf = 0; nf < 8; ++nf) acc[nf][j4] *= corr;
            Ps[(w * 16 + rg * 4 + j4) * 40 + cl]      = f2bf(p0);
            Ps[(w * 16 + rg * 4 + j4) * 40 + 16 + cl] = f2bf(p1);
        }

        // PV: O[16 x 128] += P[16 x 32] @ V[32 x 128]
        const v8s pa = *(const v8s*)&Ps[(w * 16 + cl) * 40 + rg * 8];
#pragma unroll
        for (int nf = 0; nf < 8; ++nf) {
            const v8s vb = *(const v8s*)&Vs[(nf * 16 + cl) * 40 + rg * 8];
            acc[nf] = MFMA16(pa, vb, acc[nf]);
        }
    }

    // epilogue: Y row-major, split hi/lo
#pragma unroll
    for (int nf = 0; nf < 8; ++nf) {
        const int col = h * DHEAD + nf * 16 + cl;
#pragma unroll
        for (int j4 = 0; j4 < 4; ++j4) {
            const int row = q0 + w * 16 + rg * 4 + j4;
            const float y = acc[nf][j4] / lsum[j4];
            const unsigned short hh = f2bf(y);
            Yh[(size_t)row * D_DIM + col] = hh;
            Yl[(size_t)row * D_DIM + col] = f2bf(y - bf2f(hh));
        }
    }
}

// ---------------------------------------------------------------------------
extern "C" void kernel_launch(void* const* d_in, const int* in_sizes, int n_in,
                              void* d_out, int out_size, void* d_ws, size_t ws_size,
                              hipStream_t stream)
{
    const float* x  = (const float*)d_in[0];
    const float* Wq = (const float*)d_in[1];
    const float* bq = (const float*)d_in[2];
    const float* Wk = (const float*)d_in[3];
    const float* bk = (const float*)d_in[4];
    const float* Wv = (const float*)d_in[5];
    const float* bv = (const float*)d_in[6];
    const float* Wo = (const float*)d_in[7];
    const float* bo = (const float*)d_in[8];
    float* out = (float*)d_out;

    const size_t mat = (size_t)T_DIM * D_DIM;   // 4.19M elements
    unsigned short* xh  = (unsigned short*)d_ws;          // later aliased as Yh
    unsigned short* xl  = xh + mat;                       // later aliased as Yl
    unsigned short* Qh  = xl + mat;
    unsigned short* Kh  = Qh + mat;
    unsigned short* Vth = Kh + mat;
    unsigned short* Yh  = xh;   // x dead after the 3 projections
    unsigned short* Yl  = xl;

    const int smem = 4 * 128 * 72 * 2;   // 73728 B > 64 KB -> opt in
    hipFuncSetAttribute((const void*)gemm_x3<0>, hipFuncAttributeMaxDynamicSharedMemorySize, smem);
    hipFuncSetAttribute((const void*)gemm_x3<1>, hipFuncAttributeMaxDynamicSharedMemorySize, smem);
    hipFuncSetAttribute((const void*)gemm_x3<2>, hipFuncAttributeMaxDynamicSharedMemorySize, smem);

    split_x<<<mat / (256 * 8), 256, 0, stream>>>(x, xh, xl);

    const dim3 gg(D_DIM / 128, T_DIM / 128);
    const float qscale = 0.08838834764831845f;   // 1/sqrt(128)
    gemm_x3<0><<<gg, 512, smem, stream>>>(xh, xl, Wq, bq, qscale, Qh, nullptr);
    gemm_x3<0><<<gg, 512, smem, stream>>>(xh, xl, Wk, bk, 1.0f, Kh, nullptr);
    gemm_x3<1><<<gg, 512, smem, stream>>>(xh, xl, Wv, bv, 1.0f, Vth, nullptr);

    attn_mfma<<<512, 256, 0, stream>>>(Qh, Kh, Vth, Yh, Yl);

    gemm_x3<2><<<gg, 512, smem, stream>>>(Yh, Yl, Wo, bo, 1.0f, nullptr, out);
}

// Round 3
// 344.252 us; speedup vs baseline: 5.3568x; 1.8490x over previous
//
#include <hip/hip_runtime.h>
#include <math.h>

#define T_DIM 2048
#define D_DIM 2048
#define NHEAD 16
#define DHEAD 128

typedef short v8s __attribute__((ext_vector_type(8)));   // 8 bf16 bit patterns
typedef float v4f __attribute__((ext_vector_type(4)));

#define MFMA16(a, b, c) __builtin_amdgcn_mfma_f32_16x16x32_bf16((a), (b), (c), 0, 0, 0)

__device__ __forceinline__ unsigned short f2bf(float f) {
    unsigned u = __float_as_uint(f);
    u += 0x7FFF + ((u >> 16) & 1);          // RNE
    return (unsigned short)(u >> 16);
}
__device__ __forceinline__ float bf2f(unsigned short h) {
    return __uint_as_float((unsigned)h << 16);
}
__device__ __forceinline__ unsigned pack2(unsigned short a, unsigned short b) {
    return (unsigned)a | ((unsigned)b << 16);
}

__device__ __forceinline__ void gload_lds16(const unsigned short* g, unsigned short* l) {
    __builtin_amdgcn_global_load_lds(
        (const __attribute__((address_space(1))) void*)g,
        (__attribute__((address_space(3))) void*)l, 16, 0, 0);
}

// ---------------------------------------------------------------------------
// split fp32 -> bf16 hi/lo. Used for x and for each W (once, hoisted out of
// the GEMM hot loop -- round-2 version re-split W 16x redundantly).
// ---------------------------------------------------------------------------
__global__ __launch_bounds__(256) void split_x(
    const float* __restrict__ X, unsigned short* __restrict__ Xh,
    unsigned short* __restrict__ Xl)
{
    const int i = (blockIdx.x * 256 + threadIdx.x) * 8;
    const float4 a = *(const float4*)&X[i];
    const float4 b = *(const float4*)&X[i + 4];
    const float f[8] = {a.x, a.y, a.z, a.w, b.x, b.y, b.z, b.w};
    unsigned short h[8], l[8];
#pragma unroll
    for (int e = 0; e < 8; ++e) {
        h[e] = f2bf(f[e]);
        l[e] = f2bf(f[e] - bf2f(h[e]));
    }
    uint4 hv, lv;
    hv.x = pack2(h[0], h[1]); hv.y = pack2(h[2], h[3]);
    hv.z = pack2(h[4], h[5]); hv.w = pack2(h[6], h[7]);
    lv.x = pack2(l[0], l[1]); lv.y = pack2(l[2], l[3]);
    lv.z = pack2(l[4], l[5]); lv.w = pack2(l[6], l[7]);
    *(uint4*)&Xh[i] = hv;
    *(uint4*)&Xl[i] = lv;
}

// ---------------------------------------------------------------------------
// GEMM C = A @ B^T + bias, bf16x3. All operands pre-split bf16 hi/lo.
// Tile 128(M) x 64(N), BK=64 -> grid 512 blocks (2/CU co-resident).
// 512 threads = 8 waves (4m x 2n), wave tile 32x32.
// Staging: global_load_lds 16B direct into LINEAR LDS; bank conflicts killed
// by XOR-ing the 16B-chunk index with (row&7) on BOTH the global source
// address and the ds_read address (same involution, rule-21-safe).
//  MODE 0: bf16 ((acc+bias)*scale) row-major   (Q with 1/sqrt(dh), K)
//  MODE 1: bf16 (acc+bias) transposed [n][m]   (V -> Vt)
//  MODE 2: fp32 (acc+bias) row-major           (final output)
// ---------------------------------------------------------------------------
template <int MODE>
__global__ __launch_bounds__(512, 4) void gemm_x3(
    const unsigned short* __restrict__ Ahg, const unsigned short* __restrict__ Alg,
    const unsigned short* __restrict__ Bhg, const unsigned short* __restrict__ Blg,
    const float* __restrict__ bias, float scale,
    unsigned short* __restrict__ Ob, float* __restrict__ Of)
{
    __shared__ unsigned short Ah[128 * 64];
    __shared__ unsigned short Al[128 * 64];
    __shared__ unsigned short Bh[64 * 64];
    __shared__ unsigned short Bl[64 * 64];

    const int tid = threadIdx.x;
    const int l   = tid & 63;
    const int wid = tid >> 6;
    const int wm  = wid >> 1;      // 0..3
    const int wn  = wid & 1;       // 0..1
    const int cl  = l & 15;
    const int rg  = l >> 4;
    const int m0  = blockIdx.y * 128;
    const int n0  = blockIdx.x * 64;

    const int arow = tid >> 3;     // 0..63 (+64 for second half)
    const int achk = tid & 7;
    const int axor = (achk ^ (arow & 7)) * 8;   // (arow+64)&7 == arow&7

    v4f acc[2][2];
#pragma unroll
    for (int i = 0; i < 2; ++i)
#pragma unroll
        for (int j = 0; j < 2; ++j) acc[i][j] = (v4f)0.f;

    for (int ks = 0; ks < D_DIM / 64; ++ks) {
        const int k0 = ks * 64;
        __syncthreads();
        // A hi/lo: 128 rows x 8 chunks each; B hi/lo: 64 rows x 8 chunks
        gload_lds16(&Ahg[(size_t)(m0 + arow) * D_DIM + k0 + axor],      &Ah[tid * 8]);
        gload_lds16(&Ahg[(size_t)(m0 + arow + 64) * D_DIM + k0 + axor], &Ah[(tid + 512) * 8]);
        gload_lds16(&Alg[(size_t)(m0 + arow) * D_DIM + k0 + axor],      &Al[tid * 8]);
        gload_lds16(&Alg[(size_t)(m0 + arow + 64) * D_DIM + k0 + axor], &Al[(tid + 512) * 8]);
        gload_lds16(&Bhg[(size_t)(n0 + arow) * D_DIM + k0 + axor],      &Bh[tid * 8]);
        gload_lds16(&Blg[(size_t)(n0 + arow) * D_DIM + k0 + axor],      &Bl[tid * 8]);
        __syncthreads();

#pragma unroll
        for (int kf = 0; kf < 2; ++kf) {
            const int c = kf * 4 + rg;
            v8s a_h[2], a_l[2], b_h[2], b_l[2];
#pragma unroll
            for (int mf = 0; mf < 2; ++mf) {
                const int r = wm * 32 + mf * 16 + cl;
                const int off = r * 64 + ((c ^ (r & 7)) * 8);
                a_h[mf] = *(const v8s*)&Ah[off];
                a_l[mf] = *(const v8s*)&Al[off];
            }
#pragma unroll
            for (int nf = 0; nf < 2; ++nf) {
                const int r = wn * 32 + nf * 16 + cl;
                const int off = r * 64 + ((c ^ (r & 7)) * 8);
                b_h[nf] = *(const v8s*)&Bh[off];
                b_l[nf] = *(const v8s*)&Bl[off];
            }
#pragma unroll
            for (int mf = 0; mf < 2; ++mf)
#pragma unroll
                for (int nf = 0; nf < 2; ++nf) {
                    acc[mf][nf] = MFMA16(a_h[mf], b_h[nf], acc[mf][nf]);
                    acc[mf][nf] = MFMA16(a_h[mf], b_l[nf], acc[mf][nf]);
                    acc[mf][nf] = MFMA16(a_l[mf], b_h[nf], acc[mf][nf]);
                }
        }
    }

    // epilogue: row = m0+wm*32+mf*16+rg*4+j, col = n0+wn*32+nf*16+cl
#pragma unroll
    for (int mf = 0; mf < 2; ++mf)
#pragma unroll
        for (int nf = 0; nf < 2; ++nf) {
            const int n  = n0 + wn * 32 + nf * 16 + cl;
            const int mb = m0 + wm * 32 + mf * 16 + rg * 4;
            const float bv = bias[n];
            if (MODE == 0) {
#pragma unroll
                for (int j = 0; j < 4; ++j)
                    Ob[(size_t)(mb + j) * D_DIM + n] =
                        f2bf((acc[mf][nf][j] + bv) * scale);
            } else if (MODE == 1) {
                ushort4 pk;
                pk.x = f2bf(acc[mf][nf][0] + bv);
                pk.y = f2bf(acc[mf][nf][1] + bv);
                pk.z = f2bf(acc[mf][nf][2] + bv);
                pk.w = f2bf(acc[mf][nf][3] + bv);
                *(ushort4*)&Ob[(size_t)n * D_DIM + mb] = pk;   // Vt[n][m..m+3]
            } else {
#pragma unroll
                for (int j = 0; j < 4; ++j)
                    Of[(size_t)(mb + j) * D_DIM + n] = acc[mf][nf][j] + bv;
            }
        }
}

// ---------------------------------------------------------------------------
// Causal flash attention, bf16 MFMA, KV-SPLIT partials.
// Block = 256 threads (4 waves), 64 Q rows (16/wave), BC=64 KV cols/iter.
// Grid 1024 = 16 h x 32 qt x 2 halves; half 0 covers KV tiles [0, ceil(n/2)),
// half 1 the rest (incl. diagonal). Partial (acc fp32, m, l) -> workspace;
// attn_combine merges. qt issued descending for tail packing.
// ---------------------------------------------------------------------------
__global__ __launch_bounds__(256) void attn_part(
    const unsigned short* __restrict__ Qg, const unsigned short* __restrict__ Kg,
    const unsigned short* __restrict__ Vtg,
    float* __restrict__ acc0, float* __restrict__ acc1, float* __restrict__ ml)
{
    __shared__ unsigned short Ks[64 * 136];
    __shared__ unsigned short Vs[128 * 72];
    __shared__ unsigned short Ps[64 * 72];

    const int b    = blockIdx.x;
    const int h    = b & 15;
    const int qt   = 31 - ((b >> 4) & 31);
    const int half = (b >> 9) & 1;
    const int q0   = qt * 64;
    const int tid  = threadIdx.x;
    const int l    = tid & 63;
    const int w    = tid >> 6;
    const int cl   = l & 15;
    const int rg   = l >> 4;

    // Q fragments (1/sqrt(dh) folded in by Q-GEMM epilogue)
    v8s qf[4];
#pragma unroll
    for (int kf = 0; kf < 4; ++kf)
        qf[kf] = *(const v8s*)&Qg[(size_t)(q0 + w * 16 + cl) * D_DIM +
                                  h * DHEAD + kf * 32 + rg * 8];

    v4f acc[8];
#pragma unroll
    for (int nf = 0; nf < 8; ++nf) acc[nf] = (v4f)0.f;
    float mrow[4] = {-INFINITY, -INFINITY, -INFINITY, -INFINITY};
    float lsum[4] = {0.f, 0.f, 0.f, 0.f};

    const int krow = tid >> 4, kch = tid & 15;   // K rows krow+i*16, i<4
    const int vrow = tid >> 2, vch = tid & 3;    // Vt rows vrow, vrow+64
    uint4 kr[4], vr[4];
    auto load_kv = [&](int j) {
#pragma unroll
        for (int i = 0; i < 4; ++i)
            kr[i] = *(const uint4*)&Kg[(size_t)(j * 64 + krow + i * 16) * D_DIM +
                                       h * DHEAD + kch * 8];
        const size_t vb0 = (size_t)(h * DHEAD + vrow) * D_DIM + j * 64;
        vr[0] = *(const uint4*)&Vtg[vb0 + vch * 8];
        vr[1] = *(const uint4*)&Vtg[vb0 + vch * 8 + 32];
        vr[2] = *(const uint4*)&Vtg[vb0 + (size_t)64 * D_DIM + vch * 8];
        vr[3] = *(const uint4*)&Vtg[vb0 + (size_t)64 * D_DIM + vch * 8 + 32];
    };

    const int split = (qt + 2) >> 1;            // ceil((qt+1)/2)
    const int j0 = half ? split : 0;
    const int j1 = half ? (qt + 1) : split;

    if (j0 < j1) load_kv(j0);
    for (int j = j0; j < j1; ++j) {
        __syncthreads();
#pragma unroll
        for (int i = 0; i < 4; ++i)
            *(uint4*)&Ks[(krow + i * 16) * 136 + kch * 8] = kr[i];
        *(uint4*)&Vs[vrow * 72 + vch * 8]              = vr[0];
        *(uint4*)&Vs[vrow * 72 + vch * 8 + 32]         = vr[1];
        *(uint4*)&Vs[(vrow + 64) * 72 + vch * 8]       = vr[2];
        *(uint4*)&Vs[(vrow + 64) * 72 + vch * 8 + 32]  = vr[3];
        if (j + 1 < j1) load_kv(j + 1);
        __syncthreads();

        // scores S[16 x 64] per wave
        v4f s[4];
#pragma unroll
        for (int n = 0; n < 4; ++n) s[n] = (v4f)0.f;
#pragma unroll
        for (int kf = 0; kf < 4; ++kf) {
            const int kc = kf * 32 + rg * 8;
#pragma unroll
            for (int n = 0; n < 4; ++n)
                s[n] = MFMA16(qf[kf], *(const v8s*)&Ks[(n * 16 + cl) * 136 + kc], s[n]);
        }

        const bool need_mask = (j == qt);   // only the diagonal tile
#pragma unroll
        for (int j4 = 0; j4 < 4; ++j4) {
            const int row = q0 + w * 16 + rg * 4 + j4;
            float sv[4] = {s[0][j4], s[1][j4], s[2][j4], s[3][j4]};
            if (need_mask) {
#pragma unroll
                for (int n = 0; n < 4; ++n)
                    if (j * 64 + n * 16 + cl > row) sv[n] = -INFINITY;
            }
            float mx = fmaxf(fmaxf(sv[0], sv[1]), fmaxf(sv[2], sv[3]));
            mx = fmaxf(mx, __shfl_xor(mx, 1));
            mx = fmaxf(mx, __shfl_xor(mx, 2));
            mx = fmaxf(mx, __shfl_xor(mx, 4));
            mx = fmaxf(mx, __shfl_xor(mx, 8));
            const float mnew = fmaxf(mrow[j4], mx);
            float p[4], rs = 0.f;
#pragma unroll
            for (int n = 0; n < 4; ++n) { p[n] = __expf(sv[n] - mnew); rs += p[n]; }
            rs += __shfl_xor(rs, 1);
            rs += __shfl_xor(rs, 2);
            rs += __shfl_xor(rs, 4);
            rs += __shfl_xor(rs, 8);
            const float corr = __expf(mrow[j4] - mnew);
            lsum[j4] = lsum[j4] * corr + rs;
            mrow[j4] = mnew;
#pragma unroll
            for (int nf = 0; nf < 8; ++nf) acc[nf][j4] *= corr;
            const int pr = (w * 16 + rg * 4 + j4) * 72;
#pragma unroll
            for (int n = 0; n < 4; ++n) Ps[pr + n * 16 + cl] = f2bf(p[n]);
        }
        __syncthreads();   // Ps visible (keep conservative this round)

        // PV: O[16 x 128] += P[16 x 64] @ V[64 x 128]
        v8s pa[2];
        pa[0] = *(const v8s*)&Ps[(w * 16 + cl) * 72 + rg * 8];
        pa[1] = *(const v8s*)&Ps[(w * 16 + cl) * 72 + 32 + rg * 8];
#pragma unroll
        for (int nf = 0; nf < 8; ++nf) {
#pragma unroll
            for (int kk = 0; kk < 2; ++kk) {
                const v8s vb = *(const v8s*)&Vs[(nf * 16 + cl) * 72 + kk * 32 + rg * 8];
                acc[nf] = MFMA16(pa[kk], vb, acc[nf]);
            }
        }
    }

    // epilogue: fp32 partials (no normalization), + per-row m/l
    float* __restrict__ accp = half ? acc1 : acc0;
#pragma unroll
    for (int nf = 0; nf < 8; ++nf) {
        const int col = h * DHEAD + nf * 16 + cl;
#pragma unroll
        for (int j4 = 0; j4 < 4; ++j4) {
            const int trow = q0 + w * 16 + rg * 4 + j4;
            accp[(size_t)trow * D_DIM + col] = acc[nf][j4];
        }
    }
    if (cl == 0) {
#pragma unroll
        for (int j4 = 0; j4 < 4; ++j4) {
            const int trow = q0 + w * 16 + rg * 4 + j4;
            const size_t mi = ((size_t)(half * 16 + h) * T_DIM + trow) * 2;
            ml[mi]     = mrow[j4];
            ml[mi + 1] = lsum[j4];
        }
    }
}

// ---------------------------------------------------------------------------
// Merge the two KV-half partials -> Y (bf16 hi/lo, row-major [T][D]).
// ---------------------------------------------------------------------------
__global__ __launch_bounds__(256) void attn_combine(
    const float* __restrict__ acc0, const float* __restrict__ acc1,
    const float* __restrict__ ml,
    unsigned short* __restrict__ Yh, unsigned short* __restrict__ Yl)
{
    const size_t e = ((size_t)blockIdx.x * 256 + threadIdx.x) * 8;
    const int trow = (int)(e >> 11);
    const int col  = (int)(e & 2047);
    const int h    = col >> 7;
    const float m0  = ml[((size_t)h * T_DIM + trow) * 2];
    const float l0v = ml[((size_t)h * T_DIM + trow) * 2 + 1];
    const float m1  = ml[((size_t)(16 + h) * T_DIM + trow) * 2];
    const float l1v = ml[((size_t)(16 + h) * T_DIM + trow) * 2 + 1];
    const float ms  = fmaxf(m0, m1);
    const float e0  = __expf(m0 - ms);
    const float e1  = __expf(m1 - ms);   // m1 may be -inf -> 0
    const float inv = 1.0f / (l0v * e0 + l1v * e1);
    const float s0 = e0 * inv, s1 = e1 * inv;

    const float4 a0 = *(const float4*)&acc0[e];
    const float4 a4 = *(const float4*)&acc0[e + 4];
    const float4 b0 = *(const float4*)&acc1[e];
    const float4 b4 = *(const float4*)&acc1[e + 4];
    const float y[8] = {
        a0.x * s0 + b0.x * s1, a0.y * s0 + b0.y * s1,
        a0.z * s0 + b0.z * s1, a0.w * s0 + b0.w * s1,
        a4.x * s0 + b4.x * s1, a4.y * s0 + b4.y * s1,
        a4.z * s0 + b4.z * s1, a4.w * s0 + b4.w * s1};
    unsigned short hh[8], ll[8];
#pragma unroll
    for (int i = 0; i < 8; ++i) {
        hh[i] = f2bf(y[i]);
        ll[i] = f2bf(y[i] - bf2f(hh[i]));
    }
    uint4 hv, lv;
    hv.x = pack2(hh[0], hh[1]); hv.y = pack2(hh[2], hh[3]);
    hv.z = pack2(hh[4], hh[5]); hv.w = pack2(hh[6], hh[7]);
    lv.x = pack2(ll[0], ll[1]); lv.y = pack2(ll[2], ll[3]);
    lv.z = pack2(ll[4], ll[5]); lv.w = pack2(ll[6], ll[7]);
    *(uint4*)&Yh[e] = hv;
    *(uint4*)&Yl[e] = lv;
}

// ---------------------------------------------------------------------------
extern "C" void kernel_launch(void* const* d_in, const int* in_sizes, int n_in,
                              void* d_out, int out_size, void* d_ws, size_t ws_size,
                              hipStream_t stream)
{
    const float* x  = (const float*)d_in[0];
    const float* Wq = (const float*)d_in[1];
    const float* bq = (const float*)d_in[2];
    const float* Wk = (const float*)d_in[3];
    const float* bk = (const float*)d_in[4];
    const float* Wv = (const float*)d_in[5];
    const float* bv = (const float*)d_in[6];
    const float* Wo = (const float*)d_in[7];
    const float* bo = (const float*)d_in[8];
    float* out = (float*)d_out;

    const size_t mat = (size_t)T_DIM * D_DIM;
    unsigned short* xh  = (unsigned short*)d_ws;
    unsigned short* xl  = xh + mat;
    unsigned short* Qh  = xl + mat;
    unsigned short* Kh  = Qh + mat;
    unsigned short* Vth = Kh + mat;
    unsigned short* Wh  = Vth + mat;
    unsigned short* Wl  = Wh + mat;
    float* mlf  = (float*)(Wl + mat);     // 2*16*2048*2 floats = 0.5 MB
    float* acc0 = (float*)xh;             // spans xh+xl  (x dead after QKV gemms)
    float* acc1 = (float*)Wh;             // spans Wh+Wl  (re-split for Wo later)
    unsigned short* Yh = Qh;              // combine output overwrites Q
    unsigned short* Yl = Kh;              //                         and K

    const dim3 gg(D_DIM / 64, T_DIM / 128);
    const float qscale = 0.08838834764831845f;   // 1/sqrt(128)

    split_x<<<mat / 2048, 256, 0, stream>>>(x, xh, xl);

    split_x<<<mat / 2048, 256, 0, stream>>>(Wq, Wh, Wl);
    gemm_x3<0><<<gg, 512, 0, stream>>>(xh, xl, Wh, Wl, bq, qscale, Qh, nullptr);
    split_x<<<mat / 2048, 256, 0, stream>>>(Wk, Wh, Wl);
    gemm_x3<0><<<gg, 512, 0, stream>>>(xh, xl, Wh, Wl, bk, 1.0f, Kh, nullptr);
    split_x<<<mat / 2048, 256, 0, stream>>>(Wv, Wh, Wl);
    gemm_x3<1><<<gg, 512, 0, stream>>>(xh, xl, Wh, Wl, bv, 1.0f, Vth, nullptr);

    attn_part<<<1024, 256, 0, stream>>>(Qh, Kh, Vth, acc0, acc1, mlf);
    attn_combine<<<mat / 2048, 256, 0, stream>>>(acc0, acc1, mlf, Yh, Yl);

    split_x<<<mat / 2048, 256, 0, stream>>>(Wo, Wh, Wl);
    gemm_x3<2><<<gg, 512, 0, stream>>>(Yh, Yl, Wh, Wl, bo, 1.0f, nullptr, out);
}

// Round 4
// 308.127 us; speedup vs baseline: 5.9848x; 1.1172x over previous
//
#include <hip/hip_runtime.h>
#include <math.h>

#define T_DIM 2048
#define D_DIM 2048
#define NHEAD 16
#define DHEAD 128

typedef short v8s __attribute__((ext_vector_type(8)));   // 8 bf16 bit patterns
typedef float v4f __attribute__((ext_vector_type(4)));

#define MFMA16(a, b, c) __builtin_amdgcn_mfma_f32_16x16x32_bf16((a), (b), (c), 0, 0, 0)

__device__ __forceinline__ unsigned short f2bf(float f) {
    unsigned u = __float_as_uint(f);
    u += 0x7FFF + ((u >> 16) & 1);          // RNE
    return (unsigned short)(u >> 16);
}
__device__ __forceinline__ float bf2f(unsigned short h) {
    return __uint_as_float((unsigned)h << 16);
}
__device__ __forceinline__ unsigned pack2(unsigned short a, unsigned short b) {
    return (unsigned)a | ((unsigned)b << 16);
}

__device__ __forceinline__ void gload_lds16(const unsigned short* g, unsigned short* l) {
    __builtin_amdgcn_global_load_lds(
        (const __attribute__((address_space(1))) void*)g,
        (__attribute__((address_space(3))) void*)l, 16, 0, 0);
}

// ---------------------------------------------------------------------------
// split fp32 -> bf16 hi/lo (x and each W, hoisted out of GEMM hot loops).
// ---------------------------------------------------------------------------
__global__ __launch_bounds__(256) void split_x(
    const float* __restrict__ X, unsigned short* __restrict__ Xh,
    unsigned short* __restrict__ Xl)
{
    const int i = (blockIdx.x * 256 + threadIdx.x) * 8;
    const float4 a = *(const float4*)&X[i];
    const float4 b = *(const float4*)&X[i + 4];
    const float f[8] = {a.x, a.y, a.z, a.w, b.x, b.y, b.z, b.w};
    unsigned short h[8], l[8];
#pragma unroll
    for (int e = 0; e < 8; ++e) {
        h[e] = f2bf(f[e]);
        l[e] = f2bf(f[e] - bf2f(h[e]));
    }
    uint4 hv, lv;
    hv.x = pack2(h[0], h[1]); hv.y = pack2(h[2], h[3]);
    hv.z = pack2(h[4], h[5]); hv.w = pack2(h[6], h[7]);
    lv.x = pack2(l[0], l[1]); lv.y = pack2(l[2], l[3]);
    lv.z = pack2(l[4], l[5]); lv.w = pack2(l[6], l[7]);
    *(uint4*)&Xh[i] = hv;
    *(uint4*)&Xl[i] = lv;
}

// ---------------------------------------------------------------------------
// GEMM C = A @ B^T + bias, bf16x3. (unchanged from round 3 — proven)
// ---------------------------------------------------------------------------
template <int MODE>
__global__ __launch_bounds__(512, 4) void gemm_x3(
    const unsigned short* __restrict__ Ahg, const unsigned short* __restrict__ Alg,
    const unsigned short* __restrict__ Bhg, const unsigned short* __restrict__ Blg,
    const float* __restrict__ bias, float scale,
    unsigned short* __restrict__ Ob, float* __restrict__ Of)
{
    __shared__ unsigned short Ah[128 * 64];
    __shared__ unsigned short Al[128 * 64];
    __shared__ unsigned short Bh[64 * 64];
    __shared__ unsigned short Bl[64 * 64];

    const int tid = threadIdx.x;
    const int l   = tid & 63;
    const int wid = tid >> 6;
    const int wm  = wid >> 1;
    const int wn  = wid & 1;
    const int cl  = l & 15;
    const int rg  = l >> 4;
    const int m0  = blockIdx.y * 128;
    const int n0  = blockIdx.x * 64;

    const int arow = tid >> 3;
    const int achk = tid & 7;
    const int axor = (achk ^ (arow & 7)) * 8;

    v4f acc[2][2];
#pragma unroll
    for (int i = 0; i < 2; ++i)
#pragma unroll
        for (int j = 0; j < 2; ++j) acc[i][j] = (v4f)0.f;

    for (int ks = 0; ks < D_DIM / 64; ++ks) {
        const int k0 = ks * 64;
        __syncthreads();
        gload_lds16(&Ahg[(size_t)(m0 + arow) * D_DIM + k0 + axor],      &Ah[tid * 8]);
        gload_lds16(&Ahg[(size_t)(m0 + arow + 64) * D_DIM + k0 + axor], &Ah[(tid + 512) * 8]);
        gload_lds16(&Alg[(size_t)(m0 + arow) * D_DIM + k0 + axor],      &Al[tid * 8]);
        gload_lds16(&Alg[(size_t)(m0 + arow + 64) * D_DIM + k0 + axor], &Al[(tid + 512) * 8]);
        gload_lds16(&Bhg[(size_t)(n0 + arow) * D_DIM + k0 + axor],      &Bh[tid * 8]);
        gload_lds16(&Blg[(size_t)(n0 + arow) * D_DIM + k0 + axor],      &Bl[tid * 8]);
        __syncthreads();

#pragma unroll
        for (int kf = 0; kf < 2; ++kf) {
            const int c = kf * 4 + rg;
            v8s a_h[2], a_l[2], b_h[2], b_l[2];
#pragma unroll
            for (int mf = 0; mf < 2; ++mf) {
                const int r = wm * 32 + mf * 16 + cl;
                const int off = r * 64 + ((c ^ (r & 7)) * 8);
                a_h[mf] = *(const v8s*)&Ah[off];
                a_l[mf] = *(const v8s*)&Al[off];
            }
#pragma unroll
            for (int nf = 0; nf < 2; ++nf) {
                const int r = wn * 32 + nf * 16 + cl;
                const int off = r * 64 + ((c ^ (r & 7)) * 8);
                b_h[nf] = *(const v8s*)&Bh[off];
                b_l[nf] = *(const v8s*)&Bl[off];
            }
#pragma unroll
            for (int mf = 0; mf < 2; ++mf)
#pragma unroll
                for (int nf = 0; nf < 2; ++nf) {
                    acc[mf][nf] = MFMA16(a_h[mf], b_h[nf], acc[mf][nf]);
                    acc[mf][nf] = MFMA16(a_h[mf], b_l[nf], acc[mf][nf]);
                    acc[mf][nf] = MFMA16(a_l[mf], b_h[nf], acc[mf][nf]);
                }
        }
    }

#pragma unroll
    for (int mf = 0; mf < 2; ++mf)
#pragma unroll
        for (int nf = 0; nf < 2; ++nf) {
            const int n  = n0 + wn * 32 + nf * 16 + cl;
            const int mb = m0 + wm * 32 + mf * 16 + rg * 4;
            const float bv = bias[n];
            if (MODE == 0) {
#pragma unroll
                for (int j = 0; j < 4; ++j)
                    Ob[(size_t)(mb + j) * D_DIM + n] =
                        f2bf((acc[mf][nf][j] + bv) * scale);
            } else if (MODE == 1) {
                ushort4 pk;
                pk.x = f2bf(acc[mf][nf][0] + bv);
                pk.y = f2bf(acc[mf][nf][1] + bv);
                pk.z = f2bf(acc[mf][nf][2] + bv);
                pk.w = f2bf(acc[mf][nf][3] + bv);
                *(ushort4*)&Ob[(size_t)n * D_DIM + mb] = pk;   // Vt[n][m..m+3]
            } else {
#pragma unroll
                for (int j = 0; j < 4; ++j)
                    Of[(size_t)(mb + j) * D_DIM + n] = acc[mf][nf][j] + bv;
            }
        }
}

// ---------------------------------------------------------------------------
// Causal flash attention, bf16 MFMA, IN-BLOCK KV split.
// 512 threads = 8 waves = 2 groups x 4 waves. One block per (h, qt): 64 Q rows.
// Group 0 processes KV tiles [0, split); group 1 [split, qt+1); both over the
// same Q rows in lockstep (equal iters; invalid iters masked, barriers kept).
// Partials merged in LDS at the end -> direct bf16 hi/lo Y write. No global
// partial traffic (round-3's 264 MB write amplification), no combine kernel.
// Staging via global_load_lds direct (no register round-trip), XOR-swizzled
// K/V/P (<=2-way conflicts). LDS = 2 x 40960 = 81920 B -> 2 blocks/CU.
// ---------------------------------------------------------------------------
__global__ __launch_bounds__(512, 4) void attn_fused(
    const unsigned short* __restrict__ Qg, const unsigned short* __restrict__ Kg,
    const unsigned short* __restrict__ Vtg,
    unsigned short* __restrict__ Yh, unsigned short* __restrict__ Yl)
{
    extern __shared__ char smem[];
    const int b   = blockIdx.x;
    const int h   = b & 15;
    const int qt  = 31 - (b >> 4);       // descending: long blocks first
    const int q0  = qt * 64;
    const int tid = threadIdx.x;
    const int l   = tid & 63;
    const int wid = tid >> 6;
    const int grp = wid >> 2;            // 0 or 1
    const int w   = wid & 3;             // wave within group: q rows [w*16, w*16+16)
    const int cl  = l & 15;
    const int rg  = l >> 4;
    const int tg  = tid & 255;           // group-local thread id

    char* gbase = smem + grp * 40960;
    unsigned short* Ks = (unsigned short*)gbase;             // [64][128] swz
    unsigned short* Vs = (unsigned short*)(gbase + 16384);   // [128][64] swz
    unsigned short* Ps = (unsigned short*)(gbase + 32768);   // [64][64]  swz

    const int split = (qt + 2) >> 1;               // ceil((qt+1)/2) >= 1
    const int iters = split;
    const int t0    = grp ? split : 0;
    const int tcnt  = grp ? (qt + 1 - split) : split;   // valid tiles (can be 0)

    // Q fragments (1/sqrt(dh) pre-folded by the Q-GEMM epilogue)
    v8s qf[4];
#pragma unroll
    for (int kf = 0; kf < 4; ++kf)
        qf[kf] = *(const v8s*)&Qg[(size_t)(q0 + w * 16 + cl) * D_DIM +
                                  h * DHEAD + kf * 32 + rg * 8];

    v4f acc[8];
#pragma unroll
    for (int nf = 0; nf < 8; ++nf) acc[nf] = (v4f)0.f;
    float mrow[4] = {-INFINITY, -INFINITY, -INFINITY, -INFINITY};
    float lsum[4] = {0.f, 0.f, 0.f, 0.f};

    // stage K/V tile into this group's buffers (lane-linear LDS dest,
    // inverse-swizzled global source; rule-21 involution)
    auto stage = [&](int tile) {
#pragma unroll
        for (int i = 0; i < 4; ++i) {
            const int id = i * 256 + tg;
            const int kr = id >> 4, kc = id & 15;
            gload_lds16(&Kg[(size_t)(tile * 64 + kr) * D_DIM + h * DHEAD +
                            ((kc ^ (kr & 7)) * 8)], &Ks[id * 8]);
        }
#pragma unroll
        for (int i = 0; i < 4; ++i) {
            const int id = i * 256 + tg;
            const int vr = id >> 3, vc = id & 7;
            gload_lds16(&Vtg[(size_t)(h * DHEAD + vr) * D_DIM + tile * 64 +
                             ((vc ^ (vr & 7)) * 8)], &Vs[id * 8]);
        }
    };

    for (int t = 0; t < iters; ++t) {
        __syncthreads();                 // all waves done computing prev tile
        if (t < tcnt) stage(t0 + t);
        __syncthreads();                 // drains each wave's vmcnt -> LDS valid
        if (t < tcnt) {
            const int tile = t0 + t;
            // QK^T: S[16 x 64] per wave
            v4f s[4];
#pragma unroll
            for (int n = 0; n < 4; ++n) s[n] = (v4f)0.f;
#pragma unroll
            for (int kf = 0; kf < 4; ++kf) {
#pragma unroll
                for (int n = 0; n < 4; ++n) {
                    const int kr = n * 16 + cl;
                    s[n] = MFMA16(qf[kf],
                        *(const v8s*)&Ks[kr * 128 + (((kf * 4 + rg) ^ (kr & 7)) * 8)],
                        s[n]);
                }
            }

            const bool dm = (tile == qt);
#pragma unroll
            for (int j4 = 0; j4 < 4; ++j4) {
                const int rowg = q0 + w * 16 + rg * 4 + j4;
                float sv[4] = {s[0][j4], s[1][j4], s[2][j4], s[3][j4]};
                if (dm) {
#pragma unroll
                    for (int n = 0; n < 4; ++n)
                        if (tile * 64 + n * 16 + cl > rowg) sv[n] = -INFINITY;
                }
                float mx = fmaxf(fmaxf(sv[0], sv[1]), fmaxf(sv[2], sv[3]));
                mx = fmaxf(mx, __shfl_xor(mx, 1));
                mx = fmaxf(mx, __shfl_xor(mx, 2));
                mx = fmaxf(mx, __shfl_xor(mx, 4));
                mx = fmaxf(mx, __shfl_xor(mx, 8));
                const float mnew = fmaxf(mrow[j4], mx);
                float p[4], rs = 0.f;
#pragma unroll
                for (int n = 0; n < 4; ++n) { p[n] = __expf(sv[n] - mnew); rs += p[n]; }
                rs += __shfl_xor(rs, 1);
                rs += __shfl_xor(rs, 2);
                rs += __shfl_xor(rs, 4);
                rs += __shfl_xor(rs, 8);
                const float corr = __expf(mrow[j4] - mnew);
                lsum[j4] = lsum[j4] * corr + rs;
                mrow[j4] = mnew;
#pragma unroll
                for (int nf = 0; nf < 8; ++nf) acc[nf][j4] *= corr;
                const int lr = w * 16 + rg * 4 + j4;
#pragma unroll
                for (int n = 0; n < 4; ++n)
                    Ps[lr * 64 + (((2 * n + (cl >> 3)) ^ (lr & 7)) * 8) + (cl & 7)] =
                        f2bf(p[n]);
            }
            // PV: each wave reads only its OWN P rows -> no barrier needed
            const int pr = w * 16 + cl;
            v8s pa[2];
            pa[0] = *(const v8s*)&Ps[pr * 64 + ((rg ^ (pr & 7)) * 8)];
            pa[1] = *(const v8s*)&Ps[pr * 64 + (((4 + rg) ^ (pr & 7)) * 8)];
#pragma unroll
            for (int nf = 0; nf < 8; ++nf) {
#pragma unroll
                for (int kk = 0; kk < 2; ++kk) {
                    const int vr = nf * 16 + cl;
                    const v8s vb = *(const v8s*)&Vs[vr * 64 +
                                    (((kk * 4 + rg) ^ (vr & 7)) * 8)];
                    acc[nf] = MFMA16(pa[kk], vb, acc[nf]);
                }
            }
        }
    }

    // ---- in-LDS merge of the two KV-half partials ----
    float* mAcc = (float*)(smem + 40960);    // reuses grp1's Ks+Vs (32 KB)
    float* mML  = (float*)(smem + 73728);    // reuses grp1's Ps (512 B used)

    __syncthreads();                         // all compute (both groups) done
    if (grp == 1) {
#pragma unroll
        for (int nf = 0; nf < 8; ++nf)
#pragma unroll
            for (int j4 = 0; j4 < 4; ++j4)
                mAcc[(w * 16 + rg * 4 + j4) * 128 + nf * 16 + cl] = acc[nf][j4];
        if (cl == 0) {
#pragma unroll
            for (int j4 = 0; j4 < 4; ++j4) {
                const int lr = w * 16 + rg * 4 + j4;
                mML[lr * 2]     = mrow[j4];
                mML[lr * 2 + 1] = lsum[j4];
            }
        }
    }
    __syncthreads();
    if (grp == 0) {
        float s0[4], s1[4];
#pragma unroll
        for (int j4 = 0; j4 < 4; ++j4) {
            const int lr = w * 16 + rg * 4 + j4;
            const float m1 = mML[lr * 2];
            const float l1 = mML[lr * 2 + 1];
            const float ms = fmaxf(mrow[j4], m1);
            const float e0 = __expf(mrow[j4] - ms);
            const float e1 = __expf(m1 - ms);       // -inf -> 0
            const float inv = 1.0f / (lsum[j4] * e0 + l1 * e1);
            s0[j4] = e0 * inv;
            s1[j4] = e1 * inv;
        }
#pragma unroll
        for (int nf = 0; nf < 8; ++nf) {
            const int col = h * DHEAD + nf * 16 + cl;
#pragma unroll
            for (int j4 = 0; j4 < 4; ++j4) {
                const int lr = w * 16 + rg * 4 + j4;
                const float a1 = mAcc[lr * 128 + nf * 16 + cl];
                const float y  = acc[nf][j4] * s0[j4] + a1 * s1[j4];
                const unsigned short hh = f2bf(y);
                Yh[(size_t)(q0 + lr) * D_DIM + col] = hh;
                Yl[(size_t)(q0 + lr) * D_DIM + col] = f2bf(y - bf2f(hh));
            }
        }
    }
}

// ---------------------------------------------------------------------------
extern "C" void kernel_launch(void* const* d_in, const int* in_sizes, int n_in,
                              void* d_out, int out_size, void* d_ws, size_t ws_size,
                              hipStream_t stream)
{
    const float* x  = (const float*)d_in[0];
    const float* Wq = (const float*)d_in[1];
    const float* bq = (const float*)d_in[2];
    const float* Wk = (const float*)d_in[3];
    const float* bk = (const float*)d_in[4];
    const float* Wv = (const float*)d_in[5];
    const float* bv = (const float*)d_in[6];
    const float* Wo = (const float*)d_in[7];
    const float* bo = (const float*)d_in[8];
    float* out = (float*)d_out;

    const size_t mat = (size_t)T_DIM * D_DIM;
    unsigned short* xh  = (unsigned short*)d_ws;   // becomes Yh after QKV gemms
    unsigned short* xl  = xh + mat;                // becomes Yl
    unsigned short* Qh  = xl + mat;
    unsigned short* Kh  = Qh + mat;
    unsigned short* Vth = Kh + mat;
    unsigned short* Wh  = Vth + mat;
    unsigned short* Wl  = Wh + mat;
    unsigned short* Yh  = xh;
    unsigned short* Yl  = xl;

    const int attn_lds = 81920;
    hipFuncSetAttribute((const void*)attn_fused,
                        hipFuncAttributeMaxDynamicSharedMemorySize, attn_lds);

    const dim3 gg(D_DIM / 64, T_DIM / 128);
    const float qscale = 0.08838834764831845f;   // 1/sqrt(128)

    split_x<<<mat / 2048, 256, 0, stream>>>(x, xh, xl);

    split_x<<<mat / 2048, 256, 0, stream>>>(Wq, Wh, Wl);
    gemm_x3<0><<<gg, 512, 0, stream>>>(xh, xl, Wh, Wl, bq, qscale, Qh, nullptr);
    split_x<<<mat / 2048, 256, 0, stream>>>(Wk, Wh, Wl);
    gemm_x3<0><<<gg, 512, 0, stream>>>(xh, xl, Wh, Wl, bk, 1.0f, Kh, nullptr);
    split_x<<<mat / 2048, 256, 0, stream>>>(Wv, Wh, Wl);
    gemm_x3<1><<<gg, 512, 0, stream>>>(xh, xl, Wh, Wl, bv, 1.0f, Vth, nullptr);

    attn_fused<<<512, 512, attn_lds, stream>>>(Qh, Kh, Vth, Yh, Yl);

    split_x<<<mat / 2048, 256, 0, stream>>>(Wo, Wh, Wl);
    gemm_x3<2><<<gg, 512, 0, stream>>>(Yh, Yl, Wh, Wl, bo, 1.0f, nullptr, out);
}

// Round 5
// 282.113 us; speedup vs baseline: 6.5367x; 1.0922x over previous
//
#include <hip/hip_runtime.h>
#include <math.h>

#define T_DIM 2048
#define D_DIM 2048
#define NHEAD 16
#define DHEAD 128

typedef short v8s __attribute__((ext_vector_type(8)));   // 8 bf16 bit patterns
typedef float v4f __attribute__((ext_vector_type(4)));

#define MFMA16(a, b, c) __builtin_amdgcn_mfma_f32_16x16x32_bf16((a), (b), (c), 0, 0, 0)

__device__ __forceinline__ unsigned short f2bf(float f) {
    unsigned u = __float_as_uint(f);
    u += 0x7FFF + ((u >> 16) & 1);          // RNE
    return (unsigned short)(u >> 16);
}
__device__ __forceinline__ float bf2f(unsigned short h) {
    return __uint_as_float((unsigned)h << 16);
}
__device__ __forceinline__ unsigned pack2(unsigned short a, unsigned short b) {
    return (unsigned)a | ((unsigned)b << 16);
}

__device__ __forceinline__ void gload_lds16(const unsigned short* g, unsigned short* l) {
    __builtin_amdgcn_global_load_lds(
        (const __attribute__((address_space(1))) void*)g,
        (__attribute__((address_space(3))) void*)l, 16, 0, 0);
}

// ---------------------------------------------------------------------------
// split fp32 -> bf16 hi/lo (x and each W, hoisted out of GEMM hot loops).
// ---------------------------------------------------------------------------
__global__ __launch_bounds__(256) void split_x(
    const float* __restrict__ X, unsigned short* __restrict__ Xh,
    unsigned short* __restrict__ Xl)
{
    const int i = (blockIdx.x * 256 + threadIdx.x) * 8;
    const float4 a = *(const float4*)&X[i];
    const float4 b = *(const float4*)&X[i + 4];
    const float f[8] = {a.x, a.y, a.z, a.w, b.x, b.y, b.z, b.w};
    unsigned short h[8], l[8];
#pragma unroll
    for (int e = 0; e < 8; ++e) {
        h[e] = f2bf(f[e]);
        l[e] = f2bf(f[e] - bf2f(h[e]));
    }
    uint4 hv, lv;
    hv.x = pack2(h[0], h[1]); hv.y = pack2(h[2], h[3]);
    hv.z = pack2(h[4], h[5]); hv.w = pack2(h[6], h[7]);
    lv.x = pack2(l[0], l[1]); lv.y = pack2(l[2], l[3]);
    lv.z = pack2(l[4], l[5]); lv.w = pack2(l[6], l[7]);
    *(uint4*)&Xh[i] = hv;
    *(uint4*)&Xl[i] = lv;
}

// ---------------------------------------------------------------------------
// GEMM C = A @ B^T + bias, bf16x3. (unchanged — proven)
// ---------------------------------------------------------------------------
template <int MODE>
__global__ __launch_bounds__(512, 4) void gemm_x3(
    const unsigned short* __restrict__ Ahg, const unsigned short* __restrict__ Alg,
    const unsigned short* __restrict__ Bhg, const unsigned short* __restrict__ Blg,
    const float* __restrict__ bias, float scale,
    unsigned short* __restrict__ Ob, float* __restrict__ Of)
{
    __shared__ unsigned short Ah[128 * 64];
    __shared__ unsigned short Al[128 * 64];
    __shared__ unsigned short Bh[64 * 64];
    __shared__ unsigned short Bl[64 * 64];

    const int tid = threadIdx.x;
    const int l   = tid & 63;
    const int wid = tid >> 6;
    const int wm  = wid >> 1;
    const int wn  = wid & 1;
    const int cl  = l & 15;
    const int rg  = l >> 4;
    const int m0  = blockIdx.y * 128;
    const int n0  = blockIdx.x * 64;

    const int arow = tid >> 3;
    const int achk = tid & 7;
    const int axor = (achk ^ (arow & 7)) * 8;

    v4f acc[2][2];
#pragma unroll
    for (int i = 0; i < 2; ++i)
#pragma unroll
        for (int j = 0; j < 2; ++j) acc[i][j] = (v4f)0.f;

    for (int ks = 0; ks < D_DIM / 64; ++ks) {
        const int k0 = ks * 64;
        __syncthreads();
        gload_lds16(&Ahg[(size_t)(m0 + arow) * D_DIM + k0 + axor],      &Ah[tid * 8]);
        gload_lds16(&Ahg[(size_t)(m0 + arow + 64) * D_DIM + k0 + axor], &Ah[(tid + 512) * 8]);
        gload_lds16(&Alg[(size_t)(m0 + arow) * D_DIM + k0 + axor],      &Al[tid * 8]);
        gload_lds16(&Alg[(size_t)(m0 + arow + 64) * D_DIM + k0 + axor], &Al[(tid + 512) * 8]);
        gload_lds16(&Bhg[(size_t)(n0 + arow) * D_DIM + k0 + axor],      &Bh[tid * 8]);
        gload_lds16(&Blg[(size_t)(n0 + arow) * D_DIM + k0 + axor],      &Bl[tid * 8]);
        __syncthreads();

#pragma unroll
        for (int kf = 0; kf < 2; ++kf) {
            const int c = kf * 4 + rg;
            v8s a_h[2], a_l[2], b_h[2], b_l[2];
#pragma unroll
            for (int mf = 0; mf < 2; ++mf) {
                const int r = wm * 32 + mf * 16 + cl;
                const int off = r * 64 + ((c ^ (r & 7)) * 8);
                a_h[mf] = *(const v8s*)&Ah[off];
                a_l[mf] = *(const v8s*)&Al[off];
            }
#pragma unroll
            for (int nf = 0; nf < 2; ++nf) {
                const int r = wn * 32 + nf * 16 + cl;
                const int off = r * 64 + ((c ^ (r & 7)) * 8);
                b_h[nf] = *(const v8s*)&Bh[off];
                b_l[nf] = *(const v8s*)&Bl[off];
            }
#pragma unroll
            for (int mf = 0; mf < 2; ++mf)
#pragma unroll
                for (int nf = 0; nf < 2; ++nf) {
                    acc[mf][nf] = MFMA16(a_h[mf], b_h[nf], acc[mf][nf]);
                    acc[mf][nf] = MFMA16(a_h[mf], b_l[nf], acc[mf][nf]);
                    acc[mf][nf] = MFMA16(a_l[mf], b_h[nf], acc[mf][nf]);
                }
        }
    }

#pragma unroll
    for (int mf = 0; mf < 2; ++mf)
#pragma unroll
        for (int nf = 0; nf < 2; ++nf) {
            const int n  = n0 + wn * 32 + nf * 16 + cl;
            const int mb = m0 + wm * 32 + mf * 16 + rg * 4;
            const float bv = bias[n];
            if (MODE == 0) {
#pragma unroll
                for (int j = 0; j < 4; ++j)
                    Ob[(size_t)(mb + j) * D_DIM + n] =
                        f2bf((acc[mf][nf][j] + bv) * scale);
            } else if (MODE == 1) {
                ushort4 pk;
                pk.x = f2bf(acc[mf][nf][0] + bv);
                pk.y = f2bf(acc[mf][nf][1] + bv);
                pk.z = f2bf(acc[mf][nf][2] + bv);
                pk.w = f2bf(acc[mf][nf][3] + bv);
                *(ushort4*)&Ob[(size_t)n * D_DIM + mb] = pk;   // Vt[n][m..m+3]
            } else {
#pragma unroll
                for (int j = 0; j < 4; ++j)
                    Of[(size_t)(mb + j) * D_DIM + n] = acc[mf][nf][j] + bv;
            }
        }
}

// ---------------------------------------------------------------------------
// Causal flash attention, bf16 MFMA, IN-BLOCK KV split, SWAPPED operands.
// S^T = MFMA(K_frag, Q_frag): lane (cl,rg) holds S[q=cl][kv = n*16+rg*4+jj]
// -> full q-row slice per lane: softmax reduce = 15 in-lane ops + 2 shfl_xor
// (vs 32 shfls before), state lane-local. PV also swapped
// (MFMA(Vt_frag, P_frag)): acc[nf][j] = O[q=cl][d=nf*16+rg*4+j], so rescale,
// 1/l and the group merge are lane-local; Y written as packed ushort4.
// exp in exp2-domain (log2e folded into Q scale). Same staging/swizzles.
// ---------------------------------------------------------------------------
__global__ __launch_bounds__(512, 4) void attn_fused(
    const unsigned short* __restrict__ Qg, const unsigned short* __restrict__ Kg,
    const unsigned short* __restrict__ Vtg,
    unsigned short* __restrict__ Yh, unsigned short* __restrict__ Yl)
{
    extern __shared__ char smem[];
    const int b   = blockIdx.x;
    const int h   = b & 15;
    const int qt  = 31 - (b >> 4);       // descending: long blocks first
    const int q0  = qt * 64;
    const int tid = threadIdx.x;
    const int l   = tid & 63;
    const int wid = tid >> 6;
    const int grp = wid >> 2;            // 0 or 1
    const int w   = wid & 3;             // wave: q rows [w*16, w*16+16)
    const int cl  = l & 15;
    const int rg  = l >> 4;
    const int clx = cl & 7;              // all LDS row-swizzles reduce to this
    const int tg  = tid & 255;

    char* gbase = smem + grp * 40960;
    unsigned short* Ks = (unsigned short*)gbase;             // [64][128] swz
    unsigned short* Vs = (unsigned short*)(gbase + 16384);   // [128][64] swz
    unsigned short* Ps = (unsigned short*)(gbase + 32768);   // [64][64]  swz

    const int split = (qt + 2) >> 1;               // ceil((qt+1)/2) >= 1
    const int iters = split;
    const int t0    = grp ? split : 0;
    const int tcnt  = grp ? (qt + 1 - split) : split;

    const int qrow = q0 + w * 16 + cl;   // this lane's q-row (dup over rg)

    // Q fragments (log2e/sqrt(dh) pre-folded by the Q-GEMM epilogue)
    v8s qf[4];
#pragma unroll
    for (int kf = 0; kf < 4; ++kf)
        qf[kf] = *(const v8s*)&Qg[(size_t)qrow * D_DIM + h * DHEAD + kf * 32 + rg * 8];

    v4f acc[8];                          // acc[nf][j] = O[q=cl][d=nf*16+rg*4+j]
#pragma unroll
    for (int nf = 0; nf < 8; ++nf) acc[nf] = (v4f)0.f;
    float mrow = -INFINITY;              // per-q-row state, lane-local
    float lsum = 0.f;

    auto stage = [&](int tile) {
#pragma unroll
        for (int i = 0; i < 4; ++i) {
            const int id = i * 256 + tg;
            const int kr = id >> 4, kc = id & 15;
            gload_lds16(&Kg[(size_t)(tile * 64 + kr) * D_DIM + h * DHEAD +
                            ((kc ^ (kr & 7)) * 8)], &Ks[id * 8]);
        }
#pragma unroll
        for (int i = 0; i < 4; ++i) {
            const int id = i * 256 + tg;
            const int vr = id >> 3, vc = id & 7;
            gload_lds16(&Vtg[(size_t)(h * DHEAD + vr) * D_DIM + tile * 64 +
                             ((vc ^ (vr & 7)) * 8)], &Vs[id * 8]);
        }
    };

    for (int t = 0; t < iters; ++t) {
        __syncthreads();                 // all waves done with prev tile
        if (t < tcnt) stage(t0 + t);
        __syncthreads();                 // drains vmcnt -> LDS valid
        if (t < tcnt) {
            const int tile = t0 + t;

            // QK^T swapped: st[n] reg jj = S[q=cl][kv = n*16 + rg*4 + jj]
            v4f st[4];
#pragma unroll
            for (int n = 0; n < 4; ++n) st[n] = (v4f)0.f;
            __builtin_amdgcn_s_setprio(1);
#pragma unroll
            for (int kf = 0; kf < 4; ++kf) {
#pragma unroll
                for (int n = 0; n < 4; ++n) {
                    const v8s kfr = *(const v8s*)&Ks[(n * 16 + cl) * 128 +
                                     (((kf * 4 + rg) ^ clx) * 8)];
                    st[n] = MFMA16(kfr, qf[kf], st[n]);
                }
            }
            __builtin_amdgcn_s_setprio(0);

            // causal mask (diagonal tile only) + lane-local online softmax
            float sv[4][4];
            const bool dm = (tile == qt);
#pragma unroll
            for (int n = 0; n < 4; ++n)
#pragma unroll
                for (int jj = 0; jj < 4; ++jj) {
                    float v = st[n][jj];
                    if (dm && (tile * 64 + n * 16 + rg * 4 + jj > qrow))
                        v = -INFINITY;
                    sv[n][jj] = v;
                }
            float mx = sv[0][0];
#pragma unroll
            for (int n = 0; n < 4; ++n)
#pragma unroll
                for (int jj = 0; jj < 4; ++jj) mx = fmaxf(mx, sv[n][jj]);
            mx = fmaxf(mx, __shfl_xor(mx, 16));
            mx = fmaxf(mx, __shfl_xor(mx, 32));
            const float mnew = fmaxf(mrow, mx);

            float rs = 0.f;
#pragma unroll
            for (int n = 0; n < 4; ++n) {
                float p0 = exp2f(sv[n][0] - mnew);
                float p1 = exp2f(sv[n][1] - mnew);
                float p2 = exp2f(sv[n][2] - mnew);
                float p3 = exp2f(sv[n][3] - mnew);
                rs += (p0 + p1) + (p2 + p3);
                uint2 pk;
                pk.x = pack2(f2bf(p0), f2bf(p1));
                pk.y = pack2(f2bf(p2), f2bf(p3));
                // element (row=w*16+cl, kv=n*16+rg*4): chunk = 2n+(rg>>1)
                *(uint2*)&Ps[(w * 16 + cl) * 64 +
                             (((2 * n + (rg >> 1)) ^ clx) * 8) + (rg & 1) * 4] = pk;
            }
            rs += __shfl_xor(rs, 16);
            rs += __shfl_xor(rs, 32);

            const float corr = exp2f(mrow - mnew);
            lsum = lsum * corr + rs;
            mrow = mnew;
#pragma unroll
            for (int nf = 0; nf < 8; ++nf) acc[nf] *= corr;

            // PV swapped: acc[nf] = MFMA(Vt_frag, P_frag)
            const int pr = w * 16 + cl;
            v8s pa[2];
            pa[0] = *(const v8s*)&Ps[pr * 64 + ((rg ^ clx) * 8)];
            pa[1] = *(const v8s*)&Ps[pr * 64 + (((4 + rg) ^ clx) * 8)];
            __builtin_amdgcn_s_setprio(1);
#pragma unroll
            for (int nf = 0; nf < 8; ++nf) {
#pragma unroll
                for (int kk = 0; kk < 2; ++kk) {
                    const v8s vb = *(const v8s*)&Vs[(nf * 16 + cl) * 64 +
                                    (((kk * 4 + rg) ^ clx) * 8)];
                    acc[nf] = MFMA16(vb, pa[kk], acc[nf]);
                }
            }
            __builtin_amdgcn_s_setprio(0);
        }
    }

    // ---- in-LDS merge of the two KV-half partials (lane-local in q) ----
    float* mAcc = (float*)(smem + 40960);           // [64][132] fp32, 33792 B
    float* mML  = (float*)(smem + 40960 + 33792);   // [64][2]

    const int lr = w * 16 + cl;
    __syncthreads();                     // all compute (both groups) done
    if (grp == 1) {
#pragma unroll
        for (int nf = 0; nf < 8; ++nf)
            *(v4f*)&mAcc[lr * 132 + nf * 16 + rg * 4] = acc[nf];
        if (rg == 0) {
            mML[lr * 2]     = mrow;
            mML[lr * 2 + 1] = lsum;
        }
    }
    __syncthreads();
    if (grp == 0) {
        const float m1 = mML[lr * 2];
        const float l1 = mML[lr * 2 + 1];
        const float ms = fmaxf(mrow, m1);
        const float e0 = exp2f(mrow - ms);
        const float e1 = exp2f(m1 - ms);            // -inf -> 0
        const float inv = 1.0f / (lsum * e0 + l1 * e1);
        const float s0 = e0 * inv, s1 = e1 * inv;
#pragma unroll
        for (int nf = 0; nf < 8; ++nf) {
            const v4f a1 = *(const v4f*)&mAcc[lr * 132 + nf * 16 + rg * 4];
            float y[4];
#pragma unroll
            for (int j = 0; j < 4; ++j) y[j] = acc[nf][j] * s0 + a1[j] * s1;
            ushort4 ph, pl;
            unsigned short hh;
            hh = f2bf(y[0]); ph.x = hh; pl.x = f2bf(y[0] - bf2f(hh));
            hh = f2bf(y[1]); ph.y = hh; pl.y = f2bf(y[1] - bf2f(hh));
            hh = f2bf(y[2]); ph.z = hh; pl.z = f2bf(y[2] - bf2f(hh));
            hh = f2bf(y[3]); ph.w = hh; pl.w = f2bf(y[3] - bf2f(hh));
            const size_t o = (size_t)(q0 + lr) * D_DIM + h * DHEAD + nf * 16 + rg * 4;
            *(ushort4*)&Yh[o] = ph;
            *(ushort4*)&Yl[o] = pl;
        }
    }
}

// ---------------------------------------------------------------------------
extern "C" void kernel_launch(void* const* d_in, const int* in_sizes, int n_in,
                              void* d_out, int out_size, void* d_ws, size_t ws_size,
                              hipStream_t stream)
{
    const float* x  = (const float*)d_in[0];
    const float* Wq = (const float*)d_in[1];
    const float* bq = (const float*)d_in[2];
    const float* Wk = (const float*)d_in[3];
    const float* bk = (const float*)d_in[4];
    const float* Wv = (const float*)d_in[5];
    const float* bv = (const float*)d_in[6];
    const float* Wo = (const float*)d_in[7];
    const float* bo = (const float*)d_in[8];
    float* out = (float*)d_out;

    const size_t mat = (size_t)T_DIM * D_DIM;
    unsigned short* xh  = (unsigned short*)d_ws;   // becomes Yh after QKV gemms
    unsigned short* xl  = xh + mat;                // becomes Yl
    unsigned short* Qh  = xl + mat;
    unsigned short* Kh  = Qh + mat;
    unsigned short* Vth = Kh + mat;
    unsigned short* Wh  = Vth + mat;
    unsigned short* Wl  = Wh + mat;
    unsigned short* Yh  = xh;
    unsigned short* Yl  = xl;

    const int attn_lds = 81920;
    hipFuncSetAttribute((const void*)attn_fused,
                        hipFuncAttributeMaxDynamicSharedMemorySize, attn_lds);

    const dim3 gg(D_DIM / 64, T_DIM / 128);
    // 1/sqrt(128) * log2(e): attention runs in exp2 domain (exact reparam)
    const float qscale = 0.08838834764831845f * 1.4426950408889634f;

    split_x<<<mat / 2048, 256, 0, stream>>>(x, xh, xl);

    split_x<<<mat / 2048, 256, 0, stream>>>(Wq, Wh, Wl);
    gemm_x3<0><<<gg, 512, 0, stream>>>(xh, xl, Wh, Wl, bq, qscale, Qh, nullptr);
    split_x<<<mat / 2048, 256, 0, stream>>>(Wk, Wh, Wl);
    gemm_x3<0><<<gg, 512, 0, stream>>>(xh, xl, Wh, Wl, bk, 1.0f, Kh, nullptr);
    split_x<<<mat / 2048, 256, 0, stream>>>(Wv, Wh, Wl);
    gemm_x3<1><<<gg, 512, 0, stream>>>(xh, xl, Wh, Wl, bv, 1.0f, Vth, nullptr);

    attn_fused<<<512, 512, attn_lds, stream>>>(Qh, Kh, Vth, Yh, Yl);

    split_x<<<mat / 2048, 256, 0, stream>>>(Wo, Wh, Wl);
    gemm_x3<2><<<gg, 512, 0, stream>>>(Yh, Yl, Wh, Wl, bo, 1.0f, nullptr, out);
}

// Round 6
// 266.270 us; speedup vs baseline: 6.9256x; 1.0595x over previous
//
#include <hip/hip_runtime.h>
#include <math.h>

#define T_DIM 2048
#define D_DIM 2048
#define NHEAD 16
#define DHEAD 128

typedef short v8s __attribute__((ext_vector_type(8)));   // 8 bf16 bit patterns
typedef float v4f __attribute__((ext_vector_type(4)));
typedef unsigned short ush;

#define MFMA16(a, b, c) __builtin_amdgcn_mfma_f32_16x16x32_bf16((a), (b), (c), 0, 0, 0)

__device__ __forceinline__ ush f2bf(float f) {
    unsigned u = __float_as_uint(f);
    u += 0x7FFF + ((u >> 16) & 1);          // RNE
    return (ush)(u >> 16);
}
__device__ __forceinline__ float bf2f(ush h) {
    return __uint_as_float((unsigned)h << 16);
}
__device__ __forceinline__ unsigned pack2(ush a, ush b) {
    return (unsigned)a | ((unsigned)b << 16);
}

__device__ __forceinline__ void gload_lds16(const ush* g, ush* l) {
    __builtin_amdgcn_global_load_lds(
        (const __attribute__((address_space(1))) void*)g,
        (__attribute__((address_space(3))) void*)l, 16, 0, 0);
}

// ---------------------------------------------------------------------------
// split fp32 -> bf16 hi/lo. Single-matrix version (fallback path).
// ---------------------------------------------------------------------------
__global__ __launch_bounds__(256) void split_x(
    const float* __restrict__ X, ush* __restrict__ Xh, ush* __restrict__ Xl)
{
    const int i = (blockIdx.x * 256 + threadIdx.x) * 8;
    const float4 a = *(const float4*)&X[i];
    const float4 b = *(const float4*)&X[i + 4];
    const float f[8] = {a.x, a.y, a.z, a.w, b.x, b.y, b.z, b.w};
    ush h[8], l[8];
#pragma unroll
    for (int e = 0; e < 8; ++e) {
        h[e] = f2bf(f[e]);
        l[e] = f2bf(f[e] - bf2f(h[e]));
    }
    uint4 hv, lv;
    hv.x = pack2(h[0], h[1]); hv.y = pack2(h[2], h[3]);
    hv.z = pack2(h[4], h[5]); hv.w = pack2(h[6], h[7]);
    lv.x = pack2(l[0], l[1]); lv.y = pack2(l[2], l[3]);
    lv.z = pack2(l[4], l[5]); lv.w = pack2(l[6], l[7]);
    *(uint4*)&Xh[i] = hv;
    *(uint4*)&Xl[i] = lv;
}

// Fused 5-matrix split (x, Wq, Wk, Wv, Wo) — one launch.
struct Split5Args { const float* s[5]; ush* h[5]; ush* l[5]; };

__global__ __launch_bounds__(256) void split5(Split5Args a)
{
    const int m = blockIdx.y;
    const float* X = a.s[m];
    ush* Xh = a.h[m];
    ush* Xl = a.l[m];
    const int i = (blockIdx.x * 256 + threadIdx.x) * 8;
    const float4 p = *(const float4*)&X[i];
    const float4 q = *(const float4*)&X[i + 4];
    const float f[8] = {p.x, p.y, p.z, p.w, q.x, q.y, q.z, q.w};
    ush h[8], l[8];
#pragma unroll
    for (int e = 0; e < 8; ++e) {
        h[e] = f2bf(f[e]);
        l[e] = f2bf(f[e] - bf2f(h[e]));
    }
    uint4 hv, lv;
    hv.x = pack2(h[0], h[1]); hv.y = pack2(h[2], h[3]);
    hv.z = pack2(h[4], h[5]); hv.w = pack2(h[6], h[7]);
    lv.x = pack2(l[0], l[1]); lv.y = pack2(l[2], l[3]);
    lv.z = pack2(l[4], l[5]); lv.w = pack2(l[6], l[7]);
    *(uint4*)&Xh[i] = hv;
    *(uint4*)&Xl[i] = lv;
}

// ---------------------------------------------------------------------------
// GEMM C = A @ B^T + bias, bf16x3 (fallback QKV + the Wo projection).
// Tile 128x64, BK=64. 1-D grid 512 with XCD-chunked swizzle: each XCD owns
// 2 contiguous m-panels x full n -> its A slice (2 MB hi+lo) is L2-resident.
// MODE 0: bf16 ((acc+bias)*scale) row-major; 1: bf16 transposed; 2: fp32.
// ---------------------------------------------------------------------------
template <int MODE>
__global__ __launch_bounds__(512, 4) void gemm_x3(
    const ush* __restrict__ Ahg, const ush* __restrict__ Alg,
    const ush* __restrict__ Bhg, const ush* __restrict__ Blg,
    const float* __restrict__ bias, float scale,
    ush* __restrict__ Ob, float* __restrict__ Of)
{
    __shared__ ush Ah[128 * 64];
    __shared__ ush Al[128 * 64];
    __shared__ ush Bh[64 * 64];
    __shared__ ush Bl[64 * 64];

    const int tid = threadIdx.x;
    const int l   = tid & 63;
    const int wid = tid >> 6;
    const int wm  = wid >> 1;
    const int wn  = wid & 1;
    const int cl  = l & 15;
    const int rg  = l >> 4;

    // XCD-chunked swizzle (grid 512 = 8 XCDs x 64)
    const int bid     = blockIdx.x;
    const int logical = (bid & 7) * 64 + (bid >> 3);
    const int m0      = (logical >> 5) * 128;
    const int n0      = (logical & 31) * 64;

    const int arow = tid >> 3;
    const int achk = tid & 7;
    const int axor = (achk ^ (arow & 7)) * 8;

    v4f acc[2][2];
#pragma unroll
    for (int i = 0; i < 2; ++i)
#pragma unroll
        for (int j = 0; j < 2; ++j) acc[i][j] = (v4f)0.f;

    for (int ks = 0; ks < D_DIM / 64; ++ks) {
        const int k0 = ks * 64;
        __syncthreads();
        gload_lds16(&Ahg[(size_t)(m0 + arow) * D_DIM + k0 + axor],      &Ah[tid * 8]);
        gload_lds16(&Ahg[(size_t)(m0 + arow + 64) * D_DIM + k0 + axor], &Ah[(tid + 512) * 8]);
        gload_lds16(&Alg[(size_t)(m0 + arow) * D_DIM + k0 + axor],      &Al[tid * 8]);
        gload_lds16(&Alg[(size_t)(m0 + arow + 64) * D_DIM + k0 + axor], &Al[(tid + 512) * 8]);
        gload_lds16(&Bhg[(size_t)(n0 + arow) * D_DIM + k0 + axor],      &Bh[tid * 8]);
        gload_lds16(&Blg[(size_t)(n0 + arow) * D_DIM + k0 + axor],      &Bl[tid * 8]);
        __syncthreads();

#pragma unroll
        for (int kf = 0; kf < 2; ++kf) {
            const int c = kf * 4 + rg;
            v8s a_h[2], a_l[2], b_h[2], b_l[2];
#pragma unroll
            for (int mf = 0; mf < 2; ++mf) {
                const int r = wm * 32 + mf * 16 + cl;
                const int off = r * 64 + ((c ^ (r & 7)) * 8);
                a_h[mf] = *(const v8s*)&Ah[off];
                a_l[mf] = *(const v8s*)&Al[off];
            }
#pragma unroll
            for (int nf = 0; nf < 2; ++nf) {
                const int r = wn * 32 + nf * 16 + cl;
                const int off = r * 64 + ((c ^ (r & 7)) * 8);
                b_h[nf] = *(const v8s*)&Bh[off];
                b_l[nf] = *(const v8s*)&Bl[off];
            }
#pragma unroll
            for (int mf = 0; mf < 2; ++mf)
#pragma unroll
                for (int nf = 0; nf < 2; ++nf) {
                    acc[mf][nf] = MFMA16(a_h[mf], b_h[nf], acc[mf][nf]);
                    acc[mf][nf] = MFMA16(a_h[mf], b_l[nf], acc[mf][nf]);
                    acc[mf][nf] = MFMA16(a_l[mf], b_h[nf], acc[mf][nf]);
                }
        }
    }

#pragma unroll
    for (int mf = 0; mf < 2; ++mf)
#pragma unroll
        for (int nf = 0; nf < 2; ++nf) {
            const int n  = n0 + wn * 32 + nf * 16 + cl;
            const int mb = m0 + wm * 32 + mf * 16 + rg * 4;
            const float bv = bias[n];
            if (MODE == 0) {
#pragma unroll
                for (int j = 0; j < 4; ++j)
                    Ob[(size_t)(mb + j) * D_DIM + n] =
                        f2bf((acc[mf][nf][j] + bv) * scale);
            } else if (MODE == 1) {
                ushort4 pk;
                pk.x = f2bf(acc[mf][nf][0] + bv);
                pk.y = f2bf(acc[mf][nf][1] + bv);
                pk.z = f2bf(acc[mf][nf][2] + bv);
                pk.w = f2bf(acc[mf][nf][3] + bv);
                *(ushort4*)&Ob[(size_t)n * D_DIM + mb] = pk;   // Vt[n][m..m+3]
            } else {
#pragma unroll
                for (int j = 0; j < 4; ++j)
                    Of[(size_t)(mb + j) * D_DIM + n] = acc[mf][nf][j] + bv;
            }
        }
}

// ---------------------------------------------------------------------------
// FUSED QKV GEMM, bf16x3: one block computes the Q, K and Vt tiles for its
// (m0,n0) — A staged ONCE per K-step and reused across 3 weights (3x MFMA
// per A-byte; ~1 GB less L2 traffic than 3 separate GEMMs). BK=32,
// LDS 40 KB -> 2 blocks/CU. Same XCD-chunked swizzle as gemm_x3.
// ---------------------------------------------------------------------------
__global__ __launch_bounds__(512, 4) void gemm_qkv(
    const ush* __restrict__ xh, const ush* __restrict__ xl,
    const ush* __restrict__ Wqh, const ush* __restrict__ Wql,
    const ush* __restrict__ Wkh, const ush* __restrict__ Wkl,
    const ush* __restrict__ Wvh, const ush* __restrict__ Wvl,
    const float* __restrict__ bq, const float* __restrict__ bk,
    const float* __restrict__ bv, float qscale,
    ush* __restrict__ Qo, ush* __restrict__ Ko, ush* __restrict__ Vto)
{
    extern __shared__ char qsmem[];
    ush* base = (ush*)qsmem;
    ush* Ah = base;                 // [128][32]  8 KB
    ush* Al = base + 4096;          // [128][32]  8 KB
    ush* Bhp[3], *Blp[3];
#pragma unroll
    for (int wg = 0; wg < 3; ++wg) {
        Bhp[wg] = base + 8192 + wg * 4096;        // [64][32] 4 KB each
        Blp[wg] = base + 8192 + wg * 4096 + 2048;
    }

    const int tid = threadIdx.x;
    const int l   = tid & 63;
    const int wid = tid >> 6;
    const int wm  = wid >> 1;      // 0..3
    const int wn  = wid & 1;       // 0..1
    const int cl  = l & 15;
    const int rg  = l >> 4;

    const int bid     = blockIdx.x;
    const int logical = (bid & 7) * 64 + (bid >> 3);
    const int m0      = (logical >> 5) * 128;
    const int n0      = (logical & 31) * 64;

    // A staging: 512 slots = 128 rows x 4 chunks
    const int ar = tid >> 2, ac = tid & 3;
    const int aoff = (ac ^ (ar & 3)) * 8;
    // B staging: 256 slots/buffer; waves 0-3 stage hi, 4-7 stage lo
    const int bslot = tid & 255;
    const int br = bslot >> 2, bc = bslot & 3;
    const int boff = (bc ^ (br & 3)) * 8;
    const int hilo = tid >> 8;

    const ush* bsrc[3];
    ush* bdst[3];
    bsrc[0] = hilo ? Wql : Wqh;  bdst[0] = hilo ? Blp[0] : Bhp[0];
    bsrc[1] = hilo ? Wkl : Wkh;  bdst[1] = hilo ? Blp[1] : Bhp[1];
    bsrc[2] = hilo ? Wvl : Wvh;  bdst[2] = hilo ? Blp[2] : Bhp[2];

    v4f acc[3][2][2];
#pragma unroll
    for (int wg = 0; wg < 3; ++wg)
#pragma unroll
        for (int i = 0; i < 2; ++i)
#pragma unroll
            for (int j = 0; j < 2; ++j) acc[wg][i][j] = (v4f)0.f;

    for (int ks = 0; ks < D_DIM / 32; ++ks) {
        const int k0 = ks * 32;
        __syncthreads();
        gload_lds16(&xh[(size_t)(m0 + ar) * D_DIM + k0 + aoff], &Ah[tid * 8]);
        gload_lds16(&xl[(size_t)(m0 + ar) * D_DIM + k0 + aoff], &Al[tid * 8]);
#pragma unroll
        for (int wg = 0; wg < 3; ++wg)
            gload_lds16(&bsrc[wg][(size_t)(n0 + br) * D_DIM + k0 + boff],
                        &bdst[wg][bslot * 8]);
        __syncthreads();

        v8s a_h[2], a_l[2];
#pragma unroll
        for (int mf = 0; mf < 2; ++mf) {
            const int r = wm * 32 + mf * 16 + cl;
            const int off = r * 32 + ((rg ^ (r & 3)) * 8);
            a_h[mf] = *(const v8s*)&Ah[off];
            a_l[mf] = *(const v8s*)&Al[off];
        }
#pragma unroll
        for (int wg = 0; wg < 3; ++wg) {
            v8s b_h[2], b_l[2];
#pragma unroll
            for (int nf = 0; nf < 2; ++nf) {
                const int r = wn * 32 + nf * 16 + cl;
                const int off = r * 32 + ((rg ^ (r & 3)) * 8);
                b_h[nf] = *(const v8s*)&Bhp[wg][off];
                b_l[nf] = *(const v8s*)&Blp[wg][off];
            }
#pragma unroll
            for (int mf = 0; mf < 2; ++mf)
#pragma unroll
                for (int nf = 0; nf < 2; ++nf) {
                    acc[wg][mf][nf] = MFMA16(a_h[mf], b_h[nf], acc[wg][mf][nf]);
                    acc[wg][mf][nf] = MFMA16(a_h[mf], b_l[nf], acc[wg][mf][nf]);
                    acc[wg][mf][nf] = MFMA16(a_l[mf], b_h[nf], acc[wg][mf][nf]);
                }
        }
    }

    // epilogue: Q scaled row-major, K row-major, V transposed
#pragma unroll
    for (int mf = 0; mf < 2; ++mf)
#pragma unroll
        for (int nf = 0; nf < 2; ++nf) {
            const int n  = n0 + wn * 32 + nf * 16 + cl;
            const int mb = m0 + wm * 32 + mf * 16 + rg * 4;
            const float bvq = bq[n], bvk = bk[n], bvv = bv[n];
#pragma unroll
            for (int j = 0; j < 4; ++j) {
                Qo[(size_t)(mb + j) * D_DIM + n] =
                    f2bf((acc[0][mf][nf][j] + bvq) * qscale);
                Ko[(size_t)(mb + j) * D_DIM + n] =
                    f2bf(acc[1][mf][nf][j] + bvk);
            }
            ushort4 pk;
            pk.x = f2bf(acc[2][mf][nf][0] + bvv);
            pk.y = f2bf(acc[2][mf][nf][1] + bvv);
            pk.z = f2bf(acc[2][mf][nf][2] + bvv);
            pk.w = f2bf(acc[2][mf][nf][3] + bvv);
            *(ushort4*)&Vto[(size_t)n * D_DIM + mb] = pk;
        }
}

// ---------------------------------------------------------------------------
// Causal flash attention, bf16 MFMA, in-block KV split, swapped operands.
// LDS 64 KB (Ps overlaid on Ks[0:8KB], 3rd per-tile barrier) -> 2 blocks/CU
// (round-5's 80KB request rounded over the 160KB/2 boundary = 1 block/CU).
// ---------------------------------------------------------------------------
__global__ __launch_bounds__(512, 4) void attn_fused(
    const ush* __restrict__ Qg, const ush* __restrict__ Kg,
    const ush* __restrict__ Vtg,
    ush* __restrict__ Yh, ush* __restrict__ Yl)
{
    extern __shared__ char smem[];
    const int b   = blockIdx.x;
    const int h   = b & 15;
    const int qt  = 31 - (b >> 4);       // descending: long blocks first
    const int q0  = qt * 64;
    const int tid = threadIdx.x;
    const int l   = tid & 63;
    const int wid = tid >> 6;
    const int grp = wid >> 2;            // 0 or 1
    const int w   = wid & 3;             // wave: q rows [w*16, w*16+16)
    const int cl  = l & 15;
    const int rg  = l >> 4;
    const int clx = cl & 7;
    const int tg  = tid & 255;

    char* gbase = smem + grp * 32768;
    ush* Ks = (ush*)gbase;               // [64][128] swz, 16 KB
    ush* Vs = (ush*)(gbase + 16384);     // [128][64] swz, 16 KB
    ush* Ps = Ks;                        // overlaid on Ks[0:8KB]

    const int split = (qt + 2) >> 1;
    const int iters = split;
    const int t0    = grp ? split : 0;
    const int tcnt  = grp ? (qt + 1 - split) : split;

    const int qrow = q0 + w * 16 + cl;

    v8s qf[4];
#pragma unroll
    for (int kf = 0; kf < 4; ++kf)
        qf[kf] = *(const v8s*)&Qg[(size_t)qrow * D_DIM + h * DHEAD + kf * 32 + rg * 8];

    v4f acc[8];
#pragma unroll
    for (int nf = 0; nf < 8; ++nf) acc[nf] = (v4f)0.f;
    float mrow = -INFINITY;
    float lsum = 0.f;

    auto stage = [&](int tile) {
#pragma unroll
        for (int i = 0; i < 4; ++i) {
            const int id = i * 256 + tg;
            const int kr = id >> 4, kc = id & 15;
            gload_lds16(&Kg[(size_t)(tile * 64 + kr) * D_DIM + h * DHEAD +
                            ((kc ^ (kr & 7)) * 8)], &Ks[id * 8]);
        }
#pragma unroll
        for (int i = 0; i < 4; ++i) {
            const int id = i * 256 + tg;
            const int vr = id >> 3, vc = id & 7;
            gload_lds16(&Vtg[(size_t)(h * DHEAD + vr) * D_DIM + tile * 64 +
                             ((vc ^ (vr & 7)) * 8)], &Vs[id * 8]);
        }
    };

    for (int t = 0; t < iters; ++t) {
        __syncthreads();                 // prev tile's Ks/Vs/Ps reads done
        if (t < tcnt) stage(t0 + t);
        __syncthreads();                 // staged data valid
        const bool act = (t < tcnt);
        const int tile = t0 + t;
        uint2 pk[4];
        if (act) {
            v4f st[4];
#pragma unroll
            for (int n = 0; n < 4; ++n) st[n] = (v4f)0.f;
            __builtin_amdgcn_s_setprio(1);
#pragma unroll
            for (int kf = 0; kf < 4; ++kf) {
#pragma unroll
                for (int n = 0; n < 4; ++n) {
                    const v8s kfr = *(const v8s*)&Ks[(n * 16 + cl) * 128 +
                                     (((kf * 4 + rg) ^ clx) * 8)];
                    st[n] = MFMA16(kfr, qf[kf], st[n]);
                }
            }
            __builtin_amdgcn_s_setprio(0);

            float sv[4][4];
            const bool dm = (tile == qt);
#pragma unroll
            for (int n = 0; n < 4; ++n)
#pragma unroll
                for (int jj = 0; jj < 4; ++jj) {
                    float v = st[n][jj];
                    if (dm && (tile * 64 + n * 16 + rg * 4 + jj > qrow))
                        v = -INFINITY;
                    sv[n][jj] = v;
                }
            float mx = sv[0][0];
#pragma unroll
            for (int n = 0; n < 4; ++n)
#pragma unroll
                for (int jj = 0; jj < 4; ++jj) mx = fmaxf(mx, sv[n][jj]);
            mx = fmaxf(mx, __shfl_xor(mx, 16));
            mx = fmaxf(mx, __shfl_xor(mx, 32));
            const float mnew = fmaxf(mrow, mx);

            float rs = 0.f;
#pragma unroll
            for (int n = 0; n < 4; ++n) {
                float p0 = exp2f(sv[n][0] - mnew);
                float p1 = exp2f(sv[n][1] - mnew);
                float p2 = exp2f(sv[n][2] - mnew);
                float p3 = exp2f(sv[n][3] - mnew);
                rs += (p0 + p1) + (p2 + p3);
                pk[n].x = pack2(f2bf(p0), f2bf(p1));
                pk[n].y = pack2(f2bf(p2), f2bf(p3));
            }
            rs += __shfl_xor(rs, 16);
            rs += __shfl_xor(rs, 32);

            const float corr = exp2f(mrow - mnew);
            lsum = lsum * corr + rs;
            mrow = mnew;
#pragma unroll
            for (int nf = 0; nf < 8; ++nf) acc[nf] *= corr;
        }
        __syncthreads();                 // all Ks reads done -> Ps may overwrite
        if (act) {
#pragma unroll
            for (int n = 0; n < 4; ++n)
                *(uint2*)&Ps[(w * 16 + cl) * 64 +
                             (((2 * n + (rg >> 1)) ^ clx) * 8) + (rg & 1) * 4] = pk[n];
            const int pr = w * 16 + cl;
            v8s pa[2];
            pa[0] = *(const v8s*)&Ps[pr * 64 + ((rg ^ clx) * 8)];
            pa[1] = *(const v8s*)&Ps[pr * 64 + (((4 + rg) ^ clx) * 8)];
            __builtin_amdgcn_s_setprio(1);
#pragma unroll
            for (int nf = 0; nf < 8; ++nf) {
#pragma unroll
                for (int kk = 0; kk < 2; ++kk) {
                    const v8s vb = *(const v8s*)&Vs[(nf * 16 + cl) * 64 +
                                    (((kk * 4 + rg) ^ clx) * 8)];
                    acc[nf] = MFMA16(vb, pa[kk], acc[nf]);
                }
            }
            __builtin_amdgcn_s_setprio(0);
        }
    }

    // ---- in-LDS merge of the two KV-half partials (lane-local in q) ----
    float* mAcc = (float*)smem;              // [64][132] fp32, 33792 B
    float* mML  = (float*)(smem + 33792);    // [64][2]

    const int lr = w * 16 + cl;
    __syncthreads();                         // all compute done
    if (grp == 1) {
#pragma unroll
        for (int nf = 0; nf < 8; ++nf)
            *(v4f*)&mAcc[lr * 132 + nf * 16 + rg * 4] = acc[nf];
        if (rg == 0) {
            mML[lr * 2]     = mrow;
            mML[lr * 2 + 1] = lsum;
        }
    }
    __syncthreads();
    if (grp == 0) {
        const float m1 = mML[lr * 2];
        const float l1 = mML[lr * 2 + 1];
        const float ms = fmaxf(mrow, m1);
        const float e0 = exp2f(mrow - ms);
        const float e1 = exp2f(m1 - ms);
        const float inv = 1.0f / (lsum * e0 + l1 * e1);
        const float s0 = e0 * inv, s1 = e1 * inv;
#pragma unroll
        for (int nf = 0; nf < 8; ++nf) {
            const v4f a1 = *(const v4f*)&mAcc[lr * 132 + nf * 16 + rg * 4];
            float y[4];
#pragma unroll
            for (int j = 0; j < 4; ++j) y[j] = acc[nf][j] * s0 + a1[j] * s1;
            ushort4 ph, pl;
            ush hh;
            hh = f2bf(y[0]); ph.x = hh; pl.x = f2bf(y[0] - bf2f(hh));
            hh = f2bf(y[1]); ph.y = hh; pl.y = f2bf(y[1] - bf2f(hh));
            hh = f2bf(y[2]); ph.z = hh; pl.z = f2bf(y[2] - bf2f(hh));
            hh = f2bf(y[3]); ph.w = hh; pl.w = f2bf(y[3] - bf2f(hh));
            const size_t o = (size_t)(q0 + lr) * D_DIM + h * DHEAD + nf * 16 + rg * 4;
            *(ushort4*)&Yh[o] = ph;
            *(ushort4*)&Yl[o] = pl;
        }
    }
}

// ---------------------------------------------------------------------------
extern "C" void kernel_launch(void* const* d_in, const int* in_sizes, int n_in,
                              void* d_out, int out_size, void* d_ws, size_t ws_size,
                              hipStream_t stream)
{
    const float* x  = (const float*)d_in[0];
    const float* Wq = (const float*)d_in[1];
    const float* bq = (const float*)d_in[2];
    const float* Wk = (const float*)d_in[3];
    const float* bk = (const float*)d_in[4];
    const float* Wv = (const float*)d_in[5];
    const float* bv = (const float*)d_in[6];
    const float* Wo = (const float*)d_in[7];
    const float* bo = (const float*)d_in[8];
    float* out = (float*)d_out;

    const size_t mat = (size_t)T_DIM * D_DIM;
    // 1/sqrt(128) * log2(e): attention runs in exp2 domain
    const float qscale = 0.08838834764831845f * 1.4426950408889634f;

    const int attn_lds = 65536;
    hipFuncSetAttribute((const void*)attn_fused,
                        hipFuncAttributeMaxDynamicSharedMemorySize, attn_lds);

    const size_t need_fused = 13 * mat * sizeof(ush);   // 109.1 MB

    if (ws_size >= need_fused) {
        // ---------------- fused path: 4 dispatches ----------------
        ush* xh  = (ush*)d_ws;
        ush* xl  = xh  + mat;
        ush* Qh  = xl  + mat;
        ush* Kh  = Qh  + mat;
        ush* Vth = Kh  + mat;
        ush* Wqh = Vth + mat;
        ush* Wql = Wqh + mat;
        ush* Wkh = Wql + mat;
        ush* Wkl = Wkh + mat;
        ush* Wvh = Wkl + mat;
        ush* Wvl = Wvh + mat;
        ush* Woh = Wvl + mat;
        ush* Wol = Woh + mat;
        ush* Yh  = xh;   // x dead after gemm_qkv
        ush* Yl  = xl;

        Split5Args sa;
        sa.s[0] = x;  sa.h[0] = xh;  sa.l[0] = xl;
        sa.s[1] = Wq; sa.h[1] = Wqh; sa.l[1] = Wql;
        sa.s[2] = Wk; sa.h[2] = Wkh; sa.l[2] = Wkl;
        sa.s[3] = Wv; sa.h[3] = Wvh; sa.l[3] = Wvl;
        sa.s[4] = Wo; sa.h[4] = Woh; sa.l[4] = Wol;
        split5<<<dim3(mat / 2048, 5), 256, 0, stream>>>(sa);

        hipFuncSetAttribute((const void*)gemm_qkv,
                            hipFuncAttributeMaxDynamicSharedMemorySize, 40960);
        gemm_qkv<<<512, 512, 40960, stream>>>(
            xh, xl, Wqh, Wql, Wkh, Wkl, Wvh, Wvl, bq, bk, bv, qscale,
            Qh, Kh, Vth);

        attn_fused<<<512, 512, attn_lds, stream>>>(Qh, Kh, Vth, Yh, Yl);

        gemm_x3<2><<<512, 512, 0, stream>>>(Yh, Yl, Woh, Wol, bo, 1.0f,
                                            nullptr, out);
    } else {
        // ---------------- fallback: proven round-5 sequence ----------------
        ush* xh  = (ush*)d_ws;
        ush* xl  = xh + mat;
        ush* Qh  = xl + mat;
        ush* Kh  = Qh + mat;
        ush* Vth = Kh + mat;
        ush* Wh  = Vth + mat;
        ush* Wl  = Wh + mat;
        ush* Yh  = xh;
        ush* Yl  = xl;

        split_x<<<mat / 2048, 256, 0, stream>>>(x, xh, xl);

        split_x<<<mat / 2048, 256, 0, stream>>>(Wq, Wh, Wl);
        gemm_x3<0><<<512, 512, 0, stream>>>(xh, xl, Wh, Wl, bq, qscale, Qh, nullptr);
        split_x<<<mat / 2048, 256, 0, stream>>>(Wk, Wh, Wl);
        gemm_x3<0><<<512, 512, 0, stream>>>(xh, xl, Wh, Wl, bk, 1.0f, Kh, nullptr);
        split_x<<<mat / 2048, 256, 0, stream>>>(Wv, Wh, Wl);
        gemm_x3<1><<<512, 512, 0, stream>>>(xh, xl, Wh, Wl, bv, 1.0f, Vth, nullptr);

        attn_fused<<<512, 512, attn_lds, stream>>>(Qh, Kh, Vth, Yh, Yl);

        split_x<<<mat / 2048, 256, 0, stream>>>(Wo, Wh, Wl);
        gemm_x3<2><<<512, 512, 0, stream>>>(Yh, Yl, Wh, Wl, bo, 1.0f, nullptr, out);
    }
}